// Round 6
// baseline (11904.410 us; speedup 1.0000x reference)
//
#include <hip/hip_runtime.h>
#include <hip/hip_bf16.h>
#include <stdint.h>

#define B_  4
#define N0  8192
#define S1  4096
#define S2  2048
#define KNB 32

static constexpr float EPS_IN_ = 1e-5f;

static __device__ __forceinline__ unsigned long long shfl_xor_u64(unsigned long long v, int m) {
  uint32_t lo = (uint32_t)v, hi = (uint32_t)(v >> 32);
  lo = __shfl_xor(lo, m); hi = __shfl_xor(hi, m);
  return ((unsigned long long)hi << 32) | lo;
}

// ---------------- FPS (farthest point sampling), exact lazy/pruned ----------------
// One workgroup per batch. Points counting-sorted into 16^3 spatial cells so each
// thread's 16-point chunk is spatially tight (bounding sphere g, rr). Per iteration
// a chunk is SKIPPED iff |c-g|^2 > (rr+sqrt(UB))^2*(1+2e-5): then every exact-RN
// d2(c,p) >= chunk max dist => min(dist,d2)==dist for all its points — an EXACT
// no-op (margin 1e-5 >> 3e-7 fp error). Skips never defer work, so no staleness.
// Argmax key = (bits(UB)<<32)|~orig_idx; u64-max == (max value, min ORIGINAL
// index) == numpy first-argmax — independent of sort order, so the scatter's
// nondeterministic within-cell order cannot change any output. Reduction: wave
// u64 butterfly -> owner lane stores coords, lane0 stores key (parity slots, no
// atomics) -> ONE barrier -> redundant 8-key reduce + one float4 coord read.
// d2 must match numpy exactly: (dx*dx + dy*dy) + dz*dz, all round-nearest,
// NO FMA contraction -> `#pragma clang fp contract(off)` (hipcc default is
// contract=fast-honor-pragmas; __f*_rn alone gets fused!).
template<int N, int NP, bool CHFIRST>
__global__ __launch_bounds__(512)
void fps_kernel(const float* __restrict__ pts,
                float* __restrict__ fidx_out,   // [B,NP] indices as float
                float* __restrict__ newxyz,     // [B,NP,3]
                float* __restrict__ out_t)      // [B,3,NP]
{
  constexpr int NT = 512;
  constexpr int PPT = N / NT;
  const int b = blockIdx.x;
  const int tid = threadIdx.x;
  const int lane = tid & 63;
  const int wid = tid >> 6;

  __shared__ float lxs[N], lys[N], lzs[N];      // sorted coords
  __shared__ unsigned short soid[N];            // sorted pos -> orig idx
  __shared__ unsigned short sidx[NP];           // selected orig indices
  __shared__ unsigned int cellbase[4096];       // hist -> prefix -> cursor
  __shared__ unsigned int wtot[8];
  __shared__ unsigned long long kq[2][8];
  __shared__ float4 cq[2][8];

  const float* base = pts + (size_t)b * 3 * N;  // 3N floats/batch in both layouts

  // ---- load original points (coalesced), compute 16^3 cell ids on [-4,4]^3 ----
  float ox_[PPT], oy_[PPT], oz_[PPT]; int ocell[PPT];
#pragma unroll
  for (int j = 0; j < PPT; ++j) {
    int p = tid + j * NT;
    float x, y, z;
    if (CHFIRST) { x = base[p];     y = base[N + p];   z = base[2*N + p]; }
    else         { x = base[3*p];   y = base[3*p + 1]; z = base[3*p + 2]; }
    ox_[j] = x; oy_[j] = y; oz_[j] = z;
    int cx = (int)floorf((x + 4.f) * 2.f); cx = cx < 0 ? 0 : (cx > 15 ? 15 : cx);
    int cy = (int)floorf((y + 4.f) * 2.f); cy = cy < 0 ? 0 : (cy > 15 ? 15 : cy);
    int cz = (int)floorf((z + 4.f) * 2.f); cz = cz < 0 ? 0 : (cz > 15 ? 15 : cz);
    ocell[j] = cx | (cy << 4) | (cz << 8);
  }
#pragma unroll
  for (int t = 0; t < 8; ++t) cellbase[tid + t * NT] = 0;
  __syncthreads();
#pragma unroll
  for (int j = 0; j < PPT; ++j) atomicAdd(&cellbase[ocell[j]], 1u);
  __syncthreads();
  // ---- exclusive prefix over 4096 bins (8 bins/thread + wave scan) ----
  {
    unsigned int v[8];
#pragma unroll
    for (int t = 0; t < 8; ++t) v[t] = cellbase[tid * 8 + t];
    unsigned int tot = 0;
#pragma unroll
    for (int t = 0; t < 8; ++t) { unsigned int tmp = v[t]; v[t] = tot; tot += tmp; }
    unsigned int inc = tot;
    for (int off = 1; off < 64; off <<= 1) {
      unsigned int o = __shfl_up(inc, (unsigned)off);
      if (lane >= off) inc += o;
    }
    unsigned int wexcl = inc - tot;
    if (lane == 63) wtot[wid] = inc;
    __syncthreads();
    unsigned int woff = 0;
    for (int w = 0; w < wid; ++w) woff += wtot[w];
#pragma unroll
    for (int t = 0; t < 8; ++t) cellbase[tid * 8 + t] = v[t] + wexcl + woff;
  }
  __syncthreads();
  // ---- scatter (within-cell order nondeterministic: provably output-invariant) ----
#pragma unroll
  for (int j = 0; j < PPT; ++j) {
    unsigned int pos = atomicAdd(&cellbase[ocell[j]], 1u);
    lxs[pos] = ox_[j]; lys[pos] = oy_[j]; lzs[pos] = oz_[j];
    soid[pos] = (unsigned short)(tid + j * NT);
  }
  __syncthreads();
  // ---- per-thread chunk: 16 consecutive sorted points + bounding sphere ----
  float px[PPT], py[PPT], pz[PPT], dist[PPT];
  unsigned int oid[PPT];
  float mnx = 1e30f, mny = 1e30f, mnz = 1e30f, mxx = -1e30f, mxy = -1e30f, mxz = -1e30f;
#pragma unroll
  for (int j = 0; j < PPT; ++j) {
    int p = tid * PPT + j;
    float x = lxs[p], y = lys[p], z = lzs[p];
    px[j] = x; py[j] = y; pz[j] = z; oid[j] = soid[p];
    dist[j] = 1e10f;
    mnx = fminf(mnx, x); mny = fminf(mny, y); mnz = fminf(mnz, z);
    mxx = fmaxf(mxx, x); mxy = fmaxf(mxy, y); mxz = fmaxf(mxz, z);
  }
  const float gx = (mnx + mxx) * 0.5f, gy = (mny + mxy) * 0.5f, gz = (mnz + mxz) * 0.5f;
  float r2 = 0.f;
#pragma unroll
  for (int j = 0; j < PPT; ++j) {
    float dx = px[j] - gx, dy = py[j] - gy, dz = pz[j] - gz;
    r2 = fmaxf(r2, dx * dx + dy * dy + dz * dz);
  }
  const float rr = sqrtf(r2) * 1.000002f + 1e-6f;   // safe upper bound on chunk radius

  float UB = 1e10f, sUB = sqrtf(1e10f);
  unsigned long long key = 0ull;                    // valid after i=1 (all refresh)
  float cwx = 0.f, cwy = 0.f, cwz = 0.f;

  if (tid == 0) { sidx[0] = 0; fidx_out[(size_t)b * NP] = 0.f; }
  float bx, by, bz;
  if (CHFIRST) { bx = base[0]; by = base[N]; bz = base[2*N]; }
  else         { bx = base[0]; by = base[1]; bz = base[2]; }

  for (int i = 1; i < NP; ++i) {
    const int par = i & 1;
    // ---- exact-skip test (conservative margins; any rounding is safe) ----
    float dgx = bx - gx, dgy = by - gy, dgz = bz - gz;
    float D = dgx * dgx + dgy * dgy + dgz * dgz;
    float thr = rr + sUB;
    if (D <= thr * thr * 1.00002f) {
      float nUB = -1.f;
#pragma unroll
      for (int j = 0; j < PPT; ++j) {
#pragma clang fp contract(off)
        float dx = px[j] - bx;
        float dy = py[j] - by;
        float dz = pz[j] - bz;
        float d2 = (dx * dx + dy * dy) + dz * dz;   // strict numpy order, no FMA
        float nd = fminf(dist[j], d2);
        dist[j] = nd;
        nUB = fmaxf(nUB, nd);
      }
      unsigned int nci = 0xffffffffu;
#pragma unroll
      for (int j = 0; j < PPT; ++j)
        if (dist[j] == nUB) nci = min(nci, oid[j]);
#pragma unroll
      for (int j = 0; j < PPT; ++j)
        if (oid[j] == nci) { cwx = px[j]; cwy = py[j]; cwz = pz[j]; }
      UB = nUB; sUB = sqrtf(nUB);
      key = ((unsigned long long)__float_as_uint(nUB) << 32) | (uint32_t)(~nci);
    }
    // ---- wave u64 max butterfly (max value, then min orig idx) ----
    unsigned long long red = key;
#pragma unroll
    for (int off = 32; off; off >>= 1) {
      unsigned long long o = shfl_xor_u64(red, off);
      red = (o > red) ? o : red;
    }
    if (red == key) cq[par][wid] = make_float4(cwx, cwy, cwz, 0.f);  // unique owner lane
    if (lane == 0) kq[par][wid] = red;
    __syncthreads();                                 // the ONE barrier
    unsigned long long g = kq[par][0]; int ws = 0;
#pragma unroll
    for (int w = 1; w < 8; ++w) {
      unsigned long long t = kq[par][w];
      if (t > g) { g = t; ws = w; }
    }
    float4 cc = cq[par][ws];
    bx = cc.x; by = cc.y; bz = cc.z;
    if (tid == 0) {
      unsigned int wio = ~(uint32_t)g;
      sidx[i] = (unsigned short)wio;
      fidx_out[(size_t)b * NP + i] = (float)wio;
    }
  }
  __syncthreads();
  // gather selected points from global (orig indices): newxyz [B,NP,3], out [B,3,NP]
  for (int s = tid; s < NP; s += NT) {
    int id = sidx[s];
    float x, y, z;
    if (CHFIRST) { x = base[id];   y = base[N + id];   z = base[2*N + id]; }
    else         { x = base[3*id]; y = base[3*id + 1]; z = base[3*id + 2]; }
    newxyz[((size_t)b * NP + s) * 3 + 0] = x;
    newxyz[((size_t)b * NP + s) * 3 + 1] = y;
    newxyz[((size_t)b * NP + s) * 3 + 2] = z;
    out_t[((size_t)b * 3 + 0) * NP + s] = x;
    out_t[((size_t)b * 3 + 1) * NP + s] = y;
    out_t[((size_t)b * 3 + 2) * NP + s] = z;
  }
}

// ---------------- exact kNN (32 smallest d2, ties by lowest index) ----------------
// One block per query: distances -> LDS float-bit keys, 12-bit-bin histogram
// select, deterministic ordered emit, exact (key,idx) extraction for pivot ties.
template<int N, bool CHFIRST>
__global__ __launch_bounds__(128)
void knn_kernel(const float* __restrict__ pts, const float* __restrict__ query,
                int* __restrict__ nidx, int S)
{
  constexpr int NT = 128;
  constexpr int PPT = N / NT;
  const int q = blockIdx.x, b = blockIdx.y, tid = threadIdx.x;
  __shared__ uint32_t key[N];
  __shared__ uint32_t hist[4096];
  __shared__ uint32_t gsum[NT];
  __shared__ int cnts[NT];
  __shared__ int s_pivot, s_below;
  __shared__ uint32_t wk[2];
  __shared__ int wi[2];

  const float* qp = query + ((size_t)b * S + q) * 3;
  const float qx = qp[0], qy = qp[1], qz = qp[2];
  for (int h = tid; h < 4096; h += NT) hist[h] = 0;
  __syncthreads();
  const float* base = pts + (size_t)b * 3 * N;
  for (int c = 0; c < PPT; ++c) {
    int p = c * NT + tid;
    float x, y, z;
    if (CHFIRST) { x = base[p];     y = base[N + p];   z = base[2*N + p]; }
    else         { x = base[3*p];   y = base[3*p + 1]; z = base[3*p + 2]; }
    float dx = x - qx, dy = y - qy, dz = z - qz;
    float d2 = dx * dx + dy * dy + dz * dz;      // d2 >= 0 -> bits monotone
    uint32_t k = __float_as_uint(d2);
    key[p] = k;
    atomicAdd(&hist[k >> 19], 1u);
  }
  __syncthreads();
  uint32_t ls = 0;
  for (int h = 0; h < 4096 / NT; ++h) ls += hist[tid * (4096 / NT) + h];
  gsum[tid] = ls;
  __syncthreads();
  if (tid == 0) {
    uint32_t cum = 0; int g = 0;
    while (cum + gsum[g] < (uint32_t)KNB) { cum += gsum[g]; ++g; }
    int bin = g * (4096 / NT);
    while (cum + hist[bin] < (uint32_t)KNB) { cum += hist[bin]; ++bin; }
    s_pivot = bin; s_below = (int)cum;
  }
  __syncthreads();
  const uint32_t pivot = (uint32_t)s_pivot;
  const int below = s_below;
  // deterministic ordered emit of all keys strictly below the pivot bin
  int myc = 0;
  for (int c = 0; c < PPT; ++c) {
    int p = c * NT + tid;
    if ((key[p] >> 19) < pivot) ++myc;
  }
  cnts[tid] = myc;
  __syncthreads();
  if (tid == 0) { int run = 0; for (int t = 0; t < NT; ++t) { int v = cnts[t]; cnts[t] = run; run += v; } }
  __syncthreads();
  int* outq = nidx + ((size_t)b * S + q) * KNB;
  int off = cnts[tid];
  for (int c = 0; c < PPT; ++c) {
    int p = c * NT + tid;
    if ((key[p] >> 19) < pivot) outq[off++] = p;
  }
  // remaining picks from the pivot bin: exact (key, idx) min-extraction
  const int r = KNB - below;
  for (int t = 0; t < r; ++t) {
    __syncthreads();
    uint32_t bk = 0xFFFFFFFFu; int bi = N;
    for (int c = 0; c < PPT; ++c) {
      int p = c * NT + tid;
      uint32_t kk = key[p];
      if ((kk & 0x80000000u) == 0 && (kk >> 19) == pivot) {
        if (kk < bk || (kk == bk && p < bi)) { bk = kk; bi = p; }
      }
    }
#pragma unroll
    for (int o = 32; o > 0; o >>= 1) {
      uint32_t ok = __shfl_xor(bk, o);
      int oi = __shfl_xor(bi, o);
      if (ok < bk || (ok == bk && oi < bi)) { bk = ok; bi = oi; }
    }
    if ((tid & 63) == 0) { wk[tid >> 6] = bk; wi[tid >> 6] = bi; }
    __syncthreads();
    if (tid == 0) {
      uint32_t k0 = wk[0]; int i0 = wi[0];
      if (wk[1] < k0 || (wk[1] == k0 && wi[1] < i0)) { k0 = wk[1]; i0 = wi[1]; }
      key[i0] |= 0x80000000u;   // mark taken (bit31 is free: d2 >= 0)
      outq[below + t] = i0;
    }
  }
}

// ---------------- grouping (gather + relative coords) ----------------
__global__ void gather1_kernel(const float* __restrict__ pc, const float* __restrict__ feat,
                               const int* __restrict__ nidx, const float* __restrict__ ctr,
                               __hip_bfloat16* __restrict__ g)   // [B][S1*K][6]
{
  int e = blockIdx.x * 256 + threadIdx.x;
  int b = blockIdx.y;
  if (e >= S1 * KNB) return;
  int s = e >> 5;
  int n = nidx[((size_t)b * S1 + s) * KNB + (e & 31)];
  const float* pb = pc + (size_t)b * 3 * N0;
  const float* fb = feat + (size_t)b * 3 * N0;
  const float* c = ctr + ((size_t)b * S1 + s) * 3;
  __hip_bfloat16* o = g + ((size_t)b * S1 * KNB + e) * 6;
  o[0] = __float2bfloat16(pb[n] - c[0]);
  o[1] = __float2bfloat16(pb[N0 + n] - c[1]);
  o[2] = __float2bfloat16(pb[2 * N0 + n] - c[2]);
  o[3] = __float2bfloat16(fb[n]);
  o[4] = __float2bfloat16(fb[N0 + n]);
  o[5] = __float2bfloat16(fb[2 * N0 + n]);
}

__global__ void gather2_kernel(const float* __restrict__ pc1, const float* __restrict__ f1,
                               const int* __restrict__ nidx, const float* __restrict__ ctr,
                               __hip_bfloat16* __restrict__ g)   // [B][S2*K][35]
{
  int e = blockIdx.x * 256 + threadIdx.x;
  int b = blockIdx.y;
  if (e >= S2 * KNB) return;
  int s = e >> 5;
  int n = nidx[((size_t)b * S2 + s) * KNB + (e & 31)];
  const float* p = pc1 + ((size_t)b * S1 + n) * 3;
  const float* c = ctr + ((size_t)b * S2 + s) * 3;
  const float* f = f1 + ((size_t)b * S1 + n) * 32;
  __hip_bfloat16* o = g + ((size_t)b * S2 * KNB + e) * 35;
  o[0] = __float2bfloat16(p[0] - c[0]);
  o[1] = __float2bfloat16(p[1] - c[1]);
  o[2] = __float2bfloat16(p[2] - c[2]);
#pragma unroll
  for (int ci = 0; ci < 32; ++ci) o[3 + ci] = __float2bfloat16(f[ci]);
}

// ---------------- 1x1-conv linear layer + stats partials ----------------
template<int CIN, int COUT, int TY, int EPT>
__global__ __launch_bounds__(256)
void linear_kernel(const __hip_bfloat16* __restrict__ x, const float* __restrict__ w,
                   const float* __restrict__ bias, __hip_bfloat16* __restrict__ out,
                   float* __restrict__ psum, float* __restrict__ psq, int elems)
{
  const int co = threadIdx.x, ty = threadIdx.y;
  const int blk = blockIdx.x, b = blockIdx.y;
  float wr[CIN];
#pragma unroll
  for (int ci = 0; ci < CIN; ++ci) wr[ci] = w[co * CIN + ci];
  const float bsv = bias[co];
  float ssum = 0.f, ssq = 0.f;
  const int e0 = blk * (TY * EPT) + ty * EPT;
  const __hip_bfloat16* xb = x + (size_t)b * elems * CIN;
  __hip_bfloat16* ob = out + (size_t)b * elems * COUT;
  for (int t = 0; t < EPT; ++t) {
    const int e = e0 + t;
    float acc = bsv;
#pragma unroll
    for (int ci = 0; ci < CIN; ++ci)
      acc += wr[ci] * __bfloat162float(xb[(size_t)e * CIN + ci]);
    ob[(size_t)e * COUT + co] = __float2bfloat16(acc);
    ssum += acc; ssq += acc * acc;
  }
  __shared__ float r1[TY][COUT], r2[TY][COUT];
  r1[ty][co] = ssum; r2[ty][co] = ssq;
  __syncthreads();
  if (ty == 0) {
    float a = 0.f, c = 0.f;
#pragma unroll
    for (int y = 0; y < TY; ++y) { a += r1[y][co]; c += r2[y][co]; }
    psum[((size_t)b * gridDim.x + blk) * COUT + co] = a;
    psq [((size_t)b * gridDim.x + blk) * COUT + co] = c;
  }
}

template<int COUT>
__global__ void stats_kernel(const float* __restrict__ psum, const float* __restrict__ psq,
                             int nblk, float invcnt, float* __restrict__ mean, float* __restrict__ rsv)
{
  int i = threadIdx.x;
  if (i >= B_ * COUT) return;
  int b = i / COUT, co = i % COUT;
  float s = 0.f, qq = 0.f;
  for (int k = 0; k < nblk; ++k) {
    s  += psum[((size_t)b * nblk + k) * COUT + co];
    qq += psq [((size_t)b * nblk + k) * COUT + co];
  }
  float m = s * invcnt;
  float v = qq * invcnt - m * m;
  mean[i] = m;
  rsv[i] = rsqrtf(fmaxf(v, 0.f) + EPS_IN_);
}

template<int COUT>
__global__ __launch_bounds__(256)
void norm_relu_kernel(__hip_bfloat16* __restrict__ buf, const float* __restrict__ mean,
                      const float* __restrict__ rsv, int total)
{
  const int b = blockIdx.y;
  __hip_bfloat16* bb = buf + (size_t)b * total;
  const float* mb = mean + b * COUT;
  const float* rb = rsv + b * COUT;
  for (int p = blockIdx.x * 256 + threadIdx.x; p < total; p += gridDim.x * 256) {
    int co = p & (COUT - 1);
    float v = __bfloat162float(bb[p]);
    v = fmaxf(0.f, (v - mb[co]) * rb[co]);
    bb[p] = __float2bfloat16(v);
  }
}

// ---------------- max-pool over nsample ----------------
__global__ void pool1_kernel(const __hip_bfloat16* __restrict__ buf, float* __restrict__ f1)
{
  int i = blockIdx.x * 256 + threadIdx.x;   // s*32+co
  int b = blockIdx.y;
  if (i >= S1 * 32) return;
  int s = i >> 5, co = i & 31;
  const __hip_bfloat16* bb = buf + ((size_t)b * S1 * KNB + (size_t)s * KNB) * 32 + co;
  float best = -3.4e38f;
  for (int j = 0; j < KNB; ++j) best = fmaxf(best, __bfloat162float(bb[j * 32]));
  f1[((size_t)b * S1 + s) * 32 + co] = best;
}

__global__ void pool2_kernel(const __hip_bfloat16* __restrict__ buf, float* __restrict__ out2)
{
  int i = blockIdx.x * 256 + threadIdx.x;   // s*64+co
  int b = blockIdx.y;
  if (i >= S2 * 64) return;
  int s = i >> 6, co = i & 63;
  const __hip_bfloat16* bb = buf + ((size_t)b * S2 * KNB + (size_t)s * KNB) * 64 + co;
  float best = -3.4e38f;
  for (int j = 0; j < KNB; ++j) best = fmaxf(best, __bfloat162float(bb[j * 64]));
  out2[((size_t)b * 64 + co) * S2 + s] = best;   // [B,64,S2] transposed
}

extern "C" void kernel_launch(void* const* d_in, const int* in_sizes, int n_in,
                              void* d_out, int out_size, void* d_ws, size_t ws_size,
                              hipStream_t stream)
{
  (void)in_sizes; (void)n_in; (void)out_size; (void)ws_size;
  const float* pc   = (const float*)d_in[0];
  const float* feat = (const float*)d_in[1];
  const float* w1a = (const float*)d_in[2];  const float* b1a = (const float*)d_in[3];
  const float* w1b = (const float*)d_in[4];  const float* b1b = (const float*)d_in[5];
  const float* w1c = (const float*)d_in[6];  const float* b1c = (const float*)d_in[7];
  const float* w2a = (const float*)d_in[8];  const float* b2a = (const float*)d_in[9];
  const float* w2b = (const float*)d_in[10]; const float* b2b = (const float*)d_in[11];
  const float* w2c = (const float*)d_in[12]; const float* b2c = (const float*)d_in[13];

  float* out  = (float*)d_out;
  float* out0 = out;                 // pc1^T [4,3,4096]
  float* out1 = out + 49152;         // pc2^T [4,3,2048]
  float* out2 = out + 73728;         // f2^T  [4,64,2048]
  float* out3 = out + 598016;        // idx1  [4,4096] (as float)
  float* out4 = out + 614400;        // idx2  [4,2048] (as float)

  char* wp = (char*)d_ws;
  auto carve = [&](size_t bytes) { char* p = wp; wp += (bytes + 255) & ~(size_t)255; return p; };
  __hip_bfloat16* bufA = (__hip_bfloat16*)carve((size_t)B_ * S1 * KNB * 32 * 2);
  __hip_bfloat16* bufB = (__hip_bfloat16*)carve((size_t)B_ * S1 * KNB * 32 * 2);
  int*   nidx1 = (int*)carve((size_t)B_ * S1 * KNB * 4);
  int*   nidx2 = (int*)carve((size_t)B_ * S2 * KNB * 4);
  float* pc1   = (float*)carve((size_t)B_ * S1 * 3 * 4);
  float* pc2   = (float*)carve((size_t)B_ * S2 * 3 * 4);
  float* f1    = (float*)carve((size_t)B_ * S1 * 32 * 4);
  float* psum  = (float*)carve((size_t)B_ * 512 * 64 * 4);
  float* psq   = (float*)carve((size_t)B_ * 512 * 64 * 4);
  float* mean  = (float*)carve((size_t)B_ * 64 * 4);
  float* rsv   = (float*)carve((size_t)B_ * 64 * 4);

  // ---- stage 1 ----
  fps_kernel<N0, S1, true><<<B_, 512, 0, stream>>>(pc, out3, pc1, out0);
  knn_kernel<N0, true><<<dim3(S1, B_), 128, 0, stream>>>(pc, pc1, nidx1, S1);
  gather1_kernel<<<dim3(S1 * KNB / 256, B_), 256, 0, stream>>>(pc, feat, nidx1, pc1, bufA);
  linear_kernel<6, 32, 8, 32><<<dim3(512, B_), dim3(32, 8), 0, stream>>>(bufA, w1a, b1a, bufB, psum, psq, S1 * KNB);
  stats_kernel<32><<<1, 256, 0, stream>>>(psum, psq, 512, 1.f / (S1 * KNB), mean, rsv);
  norm_relu_kernel<32><<<dim3(2048, B_), 256, 0, stream>>>(bufB, mean, rsv, S1 * KNB * 32);
  linear_kernel<32, 32, 8, 32><<<dim3(512, B_), dim3(32, 8), 0, stream>>>(bufB, w1b, b1b, bufA, psum, psq, S1 * KNB);
  stats_kernel<32><<<1, 256, 0, stream>>>(psum, psq, 512, 1.f / (S1 * KNB), mean, rsv);
  norm_relu_kernel<32><<<dim3(2048, B_), 256, 0, stream>>>(bufA, mean, rsv, S1 * KNB * 32);
  linear_kernel<32, 32, 8, 32><<<dim3(512, B_), dim3(32, 8), 0, stream>>>(bufA, w1c, b1c, bufB, psum, psq, S1 * KNB);
  stats_kernel<32><<<1, 256, 0, stream>>>(psum, psq, 512, 1.f / (S1 * KNB), mean, rsv);
  norm_relu_kernel<32><<<dim3(2048, B_), 256, 0, stream>>>(bufB, mean, rsv, S1 * KNB * 32);
  pool1_kernel<<<dim3(512, B_), 256, 0, stream>>>(bufB, f1);

  // ---- stage 2 ----
  fps_kernel<S1, S2, false><<<B_, 512, 0, stream>>>(pc1, out4, pc2, out1);
  knn_kernel<S1, false><<<dim3(S2, B_), 128, 0, stream>>>(pc1, pc2, nidx2, S2);
  gather2_kernel<<<dim3(S2 * KNB / 256, B_), 256, 0, stream>>>(pc1, f1, nidx2, pc2, bufA);
  linear_kernel<35, 64, 4, 32><<<dim3(512, B_), dim3(64, 4), 0, stream>>>(bufA, w2a, b2a, bufB, psum, psq, S2 * KNB);
  stats_kernel<64><<<1, 256, 0, stream>>>(psum, psq, 512, 1.f / (S2 * KNB), mean, rsv);
  norm_relu_kernel<64><<<dim3(2048, B_), 256, 0, stream>>>(bufB, mean, rsv, S2 * KNB * 64);
  linear_kernel<64, 64, 4, 32><<<dim3(512, B_), dim3(64, 4), 0, stream>>>(bufB, w2b, b2b, bufA, psum, psq, S2 * KNB);
  stats_kernel<64><<<1, 256, 0, stream>>>(psum, psq, 512, 1.f / (S2 * KNB), mean, rsv);
  norm_relu_kernel<64><<<dim3(2048, B_), 256, 0, stream>>>(bufA, mean, rsv, S2 * KNB * 64);
  linear_kernel<64, 64, 4, 32><<<dim3(512, B_), dim3(64, 4), 0, stream>>>(bufA, w2c, b2c, bufB, psum, psq, S2 * KNB);
  stats_kernel<64><<<1, 256, 0, stream>>>(psum, psq, 512, 1.f / (S2 * KNB), mean, rsv);
  norm_relu_kernel<64><<<dim3(2048, B_), 256, 0, stream>>>(bufB, mean, rsv, S2 * KNB * 64);
  pool2_kernel<<<dim3(512, B_), 256, 0, stream>>>(bufB, out2);
}

// Round 7
// 8512.440 us; speedup vs baseline: 1.3985x; 1.3985x over previous
//
#include <hip/hip_runtime.h>
#include <hip/hip_bf16.h>
#include <stdint.h>

#define B_  4
#define N0  8192
#define S1  4096
#define S2  2048
#define KNB 32

static constexpr float EPS_IN_ = 1e-5f;

static __device__ __forceinline__ unsigned long long shfl_xor_u64(unsigned long long v, int m) {
  uint32_t lo = (uint32_t)v, hi = (uint32_t)(v >> 32);
  lo = __shfl_xor(lo, m); hi = __shfl_xor(hi, m);
  return ((unsigned long long)hi << 32) | lo;
}

// ---------------- FPS (farthest point sampling) ----------------
// One workgroup per batch (serial argmax chain -> single-CU latency bound).
// Lean loop: phase A tracks only (bv,bi); u64 key (bits(bv)<<32)|~bi reduced
// by ONE 6-level wave butterfly (u64 max == max value, then min index ==
// numpy first-argmax); lane0 plain-stores to per-wave parity slot (NO
// atomics); ONE barrier; redundant 8-key max; winner coords via one
// broadcast ds_read_b128 from the float4 LDS table (coords never ride the
// reduction). Parity slots: kq[par] rewritten only at i+2, after barrier
// i+1 -> race-free with a single barrier per iteration.
// d2 must match numpy exactly: (dx*dx + dy*dy) + dz*dz, all round-nearest,
// NO FMA contraction -> `#pragma clang fp contract(off)` (hipcc default is
// contract=fast-honor-pragmas; __f*_rn alone gets fused!).
template<int N, int NP, bool CHFIRST>
__global__ __launch_bounds__(512)
void fps_kernel(const float* __restrict__ pts,
                float* __restrict__ fidx_out,   // [B,NP] indices as float
                float* __restrict__ newxyz,     // [B,NP,3]
                float* __restrict__ out_t)      // [B,3,NP]
{
  constexpr int NT = 512;
  constexpr int PPT = N / NT;
  const int b = blockIdx.x;
  const int tid = threadIdx.x;
  const int lane = tid & 63;
  const int wid = tid >> 6;

  __shared__ float4 lpk[N];
  __shared__ unsigned long long kq[2][8];
  __shared__ int sidx[NP];

  const float* base = pts + (size_t)b * 3 * N;  // 3N floats/batch in both layouts
  float px[PPT], py[PPT], pz[PPT], dist[PPT];
#pragma unroll
  for (int j = 0; j < PPT; ++j) {
    int p = tid + j * NT;
    float x, y, z;
    if (CHFIRST) { x = base[p];     y = base[N + p];   z = base[2*N + p]; }
    else         { x = base[3*p];   y = base[3*p + 1]; z = base[3*p + 2]; }
    px[j] = x; py[j] = y; pz[j] = z;
    lpk[p] = make_float4(x, y, z, 0.f);
    dist[j] = 1e10f;
  }
  if (tid == 0) sidx[0] = 0;
  __syncthreads();
  float bx = lpk[0].x, by = lpk[0].y, bz = lpk[0].z;

  for (int i = 1; i < NP; ++i) {
    const int par = i & 1;
    // ---- phase A: dist update + (val,idx) argmax (exact numpy arithmetic) ----
    float bv = -1.f; int bi = 0;
#pragma unroll
    for (int j = 0; j < PPT; ++j) {
#pragma clang fp contract(off)
      float dx = px[j] - bx;
      float dy = py[j] - by;
      float dz = pz[j] - bz;
      float d2 = (dx * dx + dy * dy) + dz * dz;   // strict numpy order, no FMA
      float nd = fminf(dist[j], d2);
      dist[j] = nd;
      if (nd > bv) { bv = nd; bi = tid + (j << 9); }   // first-max within thread
    }
    // ---- one u64 butterfly: (max value, then min index) ----
    unsigned long long k =
        ((unsigned long long)__float_as_uint(bv) << 32) | (uint32_t)(~(uint32_t)bi);
#pragma unroll
    for (int off = 32; off; off >>= 1) {
      unsigned long long o = shfl_xor_u64(k, off);
      k = (o > k) ? o : k;
    }
    if (lane == 0) kq[par][wid] = k;   // plain store, per-wave slot
    __syncthreads();                   // the ONE barrier
    // ---- phase B: redundant 8-key max + broadcast coord read ----
    unsigned long long g = kq[par][0];
#pragma unroll
    for (int w = 1; w < 8; ++w) {
      unsigned long long t = kq[par][w];
      g = (t > g) ? t : g;
    }
    const int wi = (int)(~(uint32_t)g);
    float4 c = lpk[wi];                // one b128 broadcast read
    bx = c.x; by = c.y; bz = c.z;
    if (tid == 0) sidx[i] = wi;
  }
  __syncthreads();
  // outputs: fidx (coalesced), newxyz [B,NP,3], transposed [B,3,NP]
  for (int s = tid; s < NP; s += NT) {
    int id = sidx[s];
    float4 c = lpk[id];
    fidx_out[(size_t)b * NP + s] = (float)id;
    newxyz[((size_t)b * NP + s) * 3 + 0] = c.x;
    newxyz[((size_t)b * NP + s) * 3 + 1] = c.y;
    newxyz[((size_t)b * NP + s) * 3 + 2] = c.z;
    out_t[((size_t)b * 3 + 0) * NP + s] = c.x;
    out_t[((size_t)b * 3 + 1) * NP + s] = c.y;
    out_t[((size_t)b * 3 + 2) * NP + s] = c.z;
  }
}

// ---------------- exact kNN (32 smallest d2, ties by lowest index) ----------------
// One block per query: distances -> LDS float-bit keys, 12-bit-bin histogram
// select, deterministic ordered emit, exact (key,idx) extraction for pivot ties.
template<int N, bool CHFIRST>
__global__ __launch_bounds__(128)
void knn_kernel(const float* __restrict__ pts, const float* __restrict__ query,
                int* __restrict__ nidx, int S)
{
  constexpr int NT = 128;
  constexpr int PPT = N / NT;
  const int q = blockIdx.x, b = blockIdx.y, tid = threadIdx.x;
  __shared__ uint32_t key[N];
  __shared__ uint32_t hist[4096];
  __shared__ uint32_t gsum[NT];
  __shared__ int cnts[NT];
  __shared__ int s_pivot, s_below;
  __shared__ uint32_t wk[2];
  __shared__ int wi[2];

  const float* qp = query + ((size_t)b * S + q) * 3;
  const float qx = qp[0], qy = qp[1], qz = qp[2];
  for (int h = tid; h < 4096; h += NT) hist[h] = 0;
  __syncthreads();
  const float* base = pts + (size_t)b * 3 * N;
  for (int c = 0; c < PPT; ++c) {
    int p = c * NT + tid;
    float x, y, z;
    if (CHFIRST) { x = base[p];     y = base[N + p];   z = base[2*N + p]; }
    else         { x = base[3*p];   y = base[3*p + 1]; z = base[3*p + 2]; }
    float dx = x - qx, dy = y - qy, dz = z - qz;
    float d2 = dx * dx + dy * dy + dz * dz;      // d2 >= 0 -> bits monotone
    uint32_t k = __float_as_uint(d2);
    key[p] = k;
    atomicAdd(&hist[k >> 19], 1u);
  }
  __syncthreads();
  uint32_t ls = 0;
  for (int h = 0; h < 4096 / NT; ++h) ls += hist[tid * (4096 / NT) + h];
  gsum[tid] = ls;
  __syncthreads();
  if (tid == 0) {
    uint32_t cum = 0; int g = 0;
    while (cum + gsum[g] < (uint32_t)KNB) { cum += gsum[g]; ++g; }
    int bin = g * (4096 / NT);
    while (cum + hist[bin] < (uint32_t)KNB) { cum += hist[bin]; ++bin; }
    s_pivot = bin; s_below = (int)cum;
  }
  __syncthreads();
  const uint32_t pivot = (uint32_t)s_pivot;
  const int below = s_below;
  // deterministic ordered emit of all keys strictly below the pivot bin
  int myc = 0;
  for (int c = 0; c < PPT; ++c) {
    int p = c * NT + tid;
    if ((key[p] >> 19) < pivot) ++myc;
  }
  cnts[tid] = myc;
  __syncthreads();
  if (tid == 0) { int run = 0; for (int t = 0; t < NT; ++t) { int v = cnts[t]; cnts[t] = run; run += v; } }
  __syncthreads();
  int* outq = nidx + ((size_t)b * S + q) * KNB;
  int off = cnts[tid];
  for (int c = 0; c < PPT; ++c) {
    int p = c * NT + tid;
    if ((key[p] >> 19) < pivot) outq[off++] = p;
  }
  // remaining picks from the pivot bin: exact (key, idx) min-extraction
  const int r = KNB - below;
  for (int t = 0; t < r; ++t) {
    __syncthreads();
    uint32_t bk = 0xFFFFFFFFu; int bi = N;
    for (int c = 0; c < PPT; ++c) {
      int p = c * NT + tid;
      uint32_t kk = key[p];
      if ((kk & 0x80000000u) == 0 && (kk >> 19) == pivot) {
        if (kk < bk || (kk == bk && p < bi)) { bk = kk; bi = p; }
      }
    }
#pragma unroll
    for (int o = 32; o > 0; o >>= 1) {
      uint32_t ok = __shfl_xor(bk, o);
      int oi = __shfl_xor(bi, o);
      if (ok < bk || (ok == bk && oi < bi)) { bk = ok; bi = oi; }
    }
    if ((tid & 63) == 0) { wk[tid >> 6] = bk; wi[tid >> 6] = bi; }
    __syncthreads();
    if (tid == 0) {
      uint32_t k0 = wk[0]; int i0 = wi[0];
      if (wk[1] < k0 || (wk[1] == k0 && wi[1] < i0)) { k0 = wk[1]; i0 = wi[1]; }
      key[i0] |= 0x80000000u;   // mark taken (bit31 is free: d2 >= 0)
      outq[below + t] = i0;
    }
  }
}

// ---------------- grouping (gather + relative coords) ----------------
__global__ void gather1_kernel(const float* __restrict__ pc, const float* __restrict__ feat,
                               const int* __restrict__ nidx, const float* __restrict__ ctr,
                               __hip_bfloat16* __restrict__ g)   // [B][S1*K][6]
{
  int e = blockIdx.x * 256 + threadIdx.x;
  int b = blockIdx.y;
  if (e >= S1 * KNB) return;
  int s = e >> 5;
  int n = nidx[((size_t)b * S1 + s) * KNB + (e & 31)];
  const float* pb = pc + (size_t)b * 3 * N0;
  const float* fb = feat + (size_t)b * 3 * N0;
  const float* c = ctr + ((size_t)b * S1 + s) * 3;
  __hip_bfloat16* o = g + ((size_t)b * S1 * KNB + e) * 6;
  o[0] = __float2bfloat16(pb[n] - c[0]);
  o[1] = __float2bfloat16(pb[N0 + n] - c[1]);
  o[2] = __float2bfloat16(pb[2 * N0 + n] - c[2]);
  o[3] = __float2bfloat16(fb[n]);
  o[4] = __float2bfloat16(fb[N0 + n]);
  o[5] = __float2bfloat16(fb[2 * N0 + n]);
}

__global__ void gather2_kernel(const float* __restrict__ pc1, const float* __restrict__ f1,
                               const int* __restrict__ nidx, const float* __restrict__ ctr,
                               __hip_bfloat16* __restrict__ g)   // [B][S2*K][35]
{
  int e = blockIdx.x * 256 + threadIdx.x;
  int b = blockIdx.y;
  if (e >= S2 * KNB) return;
  int s = e >> 5;
  int n = nidx[((size_t)b * S2 + s) * KNB + (e & 31)];
  const float* p = pc1 + ((size_t)b * S1 + n) * 3;
  const float* c = ctr + ((size_t)b * S2 + s) * 3;
  const float* f = f1 + ((size_t)b * S1 + n) * 32;
  __hip_bfloat16* o = g + ((size_t)b * S2 * KNB + e) * 35;
  o[0] = __float2bfloat16(p[0] - c[0]);
  o[1] = __float2bfloat16(p[1] - c[1]);
  o[2] = __float2bfloat16(p[2] - c[2]);
#pragma unroll
  for (int ci = 0; ci < 32; ++ci) o[3 + ci] = __float2bfloat16(f[ci]);
}

// ---------------- 1x1-conv linear layer + stats partials ----------------
template<int CIN, int COUT, int TY, int EPT>
__global__ __launch_bounds__(256)
void linear_kernel(const __hip_bfloat16* __restrict__ x, const float* __restrict__ w,
                   const float* __restrict__ bias, __hip_bfloat16* __restrict__ out,
                   float* __restrict__ psum, float* __restrict__ psq, int elems)
{
  const int co = threadIdx.x, ty = threadIdx.y;
  const int blk = blockIdx.x, b = blockIdx.y;
  float wr[CIN];
#pragma unroll
  for (int ci = 0; ci < CIN; ++ci) wr[ci] = w[co * CIN + ci];
  const float bsv = bias[co];
  float ssum = 0.f, ssq = 0.f;
  const int e0 = blk * (TY * EPT) + ty * EPT;
  const __hip_bfloat16* xb = x + (size_t)b * elems * CIN;
  __hip_bfloat16* ob = out + (size_t)b * elems * COUT;
  for (int t = 0; t < EPT; ++t) {
    const int e = e0 + t;
    float acc = bsv;
#pragma unroll
    for (int ci = 0; ci < CIN; ++ci)
      acc += wr[ci] * __bfloat162float(xb[(size_t)e * CIN + ci]);
    ob[(size_t)e * COUT + co] = __float2bfloat16(acc);
    ssum += acc; ssq += acc * acc;
  }
  __shared__ float r1[TY][COUT], r2[TY][COUT];
  r1[ty][co] = ssum; r2[ty][co] = ssq;
  __syncthreads();
  if (ty == 0) {
    float a = 0.f, c = 0.f;
#pragma unroll
    for (int y = 0; y < TY; ++y) { a += r1[y][co]; c += r2[y][co]; }
    psum[((size_t)b * gridDim.x + blk) * COUT + co] = a;
    psq [((size_t)b * gridDim.x + blk) * COUT + co] = c;
  }
}

template<int COUT>
__global__ void stats_kernel(const float* __restrict__ psum, const float* __restrict__ psq,
                             int nblk, float invcnt, float* __restrict__ mean, float* __restrict__ rsv)
{
  int i = threadIdx.x;
  if (i >= B_ * COUT) return;
  int b = i / COUT, co = i % COUT;
  float s = 0.f, qq = 0.f;
  for (int k = 0; k < nblk; ++k) {
    s  += psum[((size_t)b * nblk + k) * COUT + co];
    qq += psq [((size_t)b * nblk + k) * COUT + co];
  }
  float m = s * invcnt;
  float v = qq * invcnt - m * m;
  mean[i] = m;
  rsv[i] = rsqrtf(fmaxf(v, 0.f) + EPS_IN_);
}

template<int COUT>
__global__ __launch_bounds__(256)
void norm_relu_kernel(__hip_bfloat16* __restrict__ buf, const float* __restrict__ mean,
                      const float* __restrict__ rsv, int total)
{
  const int b = blockIdx.y;
  __hip_bfloat16* bb = buf + (size_t)b * total;
  const float* mb = mean + b * COUT;
  const float* rb = rsv + b * COUT;
  for (int p = blockIdx.x * 256 + threadIdx.x; p < total; p += gridDim.x * 256) {
    int co = p & (COUT - 1);
    float v = __bfloat162float(bb[p]);
    v = fmaxf(0.f, (v - mb[co]) * rb[co]);
    bb[p] = __float2bfloat16(v);
  }
}

// ---------------- max-pool over nsample ----------------
__global__ void pool1_kernel(const __hip_bfloat16* __restrict__ buf, float* __restrict__ f1)
{
  int i = blockIdx.x * 256 + threadIdx.x;   // s*32+co
  int b = blockIdx.y;
  if (i >= S1 * 32) return;
  int s = i >> 5, co = i & 31;
  const __hip_bfloat16* bb = buf + ((size_t)b * S1 * KNB + (size_t)s * KNB) * 32 + co;
  float best = -3.4e38f;
  for (int j = 0; j < KNB; ++j) best = fmaxf(best, __bfloat162float(bb[j * 32]));
  f1[((size_t)b * S1 + s) * 32 + co] = best;
}

__global__ void pool2_kernel(const __hip_bfloat16* __restrict__ buf, float* __restrict__ out2)
{
  int i = blockIdx.x * 256 + threadIdx.x;   // s*64+co
  int b = blockIdx.y;
  if (i >= S2 * 64) return;
  int s = i >> 6, co = i & 63;
  const __hip_bfloat16* bb = buf + ((size_t)b * S2 * KNB + (size_t)s * KNB) * 64 + co;
  float best = -3.4e38f;
  for (int j = 0; j < KNB; ++j) best = fmaxf(best, __bfloat162float(bb[j * 64]));
  out2[((size_t)b * 64 + co) * S2 + s] = best;   // [B,64,S2] transposed
}

extern "C" void kernel_launch(void* const* d_in, const int* in_sizes, int n_in,
                              void* d_out, int out_size, void* d_ws, size_t ws_size,
                              hipStream_t stream)
{
  (void)in_sizes; (void)n_in; (void)out_size; (void)ws_size;
  const float* pc   = (const float*)d_in[0];
  const float* feat = (const float*)d_in[1];
  const float* w1a = (const float*)d_in[2];  const float* b1a = (const float*)d_in[3];
  const float* w1b = (const float*)d_in[4];  const float* b1b = (const float*)d_in[5];
  const float* w1c = (const float*)d_in[6];  const float* b1c = (const float*)d_in[7];
  const float* w2a = (const float*)d_in[8];  const float* b2a = (const float*)d_in[9];
  const float* w2b = (const float*)d_in[10]; const float* b2b = (const float*)d_in[11];
  const float* w2c = (const float*)d_in[12]; const float* b2c = (const float*)d_in[13];

  float* out  = (float*)d_out;
  float* out0 = out;                 // pc1^T [4,3,4096]
  float* out1 = out + 49152;         // pc2^T [4,3,2048]
  float* out2 = out + 73728;         // f2^T  [4,64,2048]
  float* out3 = out + 598016;        // idx1  [4,4096] (as float)
  float* out4 = out + 614400;        // idx2  [4,2048] (as float)

  char* wp = (char*)d_ws;
  auto carve = [&](size_t bytes) { char* p = wp; wp += (bytes + 255) & ~(size_t)255; return p; };
  __hip_bfloat16* bufA = (__hip_bfloat16*)carve((size_t)B_ * S1 * KNB * 32 * 2);
  __hip_bfloat16* bufB = (__hip_bfloat16*)carve((size_t)B_ * S1 * KNB * 32 * 2);
  int*   nidx1 = (int*)carve((size_t)B_ * S1 * KNB * 4);
  int*   nidx2 = (int*)carve((size_t)B_ * S2 * KNB * 4);
  float* pc1   = (float*)carve((size_t)B_ * S1 * 3 * 4);
  float* pc2   = (float*)carve((size_t)B_ * S2 * 3 * 4);
  float* f1    = (float*)carve((size_t)B_ * S1 * 32 * 4);
  float* psum  = (float*)carve((size_t)B_ * 512 * 64 * 4);
  float* psq   = (float*)carve((size_t)B_ * 512 * 64 * 4);
  float* mean  = (float*)carve((size_t)B_ * 64 * 4);
  float* rsv   = (float*)carve((size_t)B_ * 64 * 4);

  // ---- stage 1 ----
  fps_kernel<N0, S1, true><<<B_, 512, 0, stream>>>(pc, out3, pc1, out0);
  knn_kernel<N0, true><<<dim3(S1, B_), 128, 0, stream>>>(pc, pc1, nidx1, S1);
  gather1_kernel<<<dim3(S1 * KNB / 256, B_), 256, 0, stream>>>(pc, feat, nidx1, pc1, bufA);
  linear_kernel<6, 32, 8, 32><<<dim3(512, B_), dim3(32, 8), 0, stream>>>(bufA, w1a, b1a, bufB, psum, psq, S1 * KNB);
  stats_kernel<32><<<1, 256, 0, stream>>>(psum, psq, 512, 1.f / (S1 * KNB), mean, rsv);
  norm_relu_kernel<32><<<dim3(2048, B_), 256, 0, stream>>>(bufB, mean, rsv, S1 * KNB * 32);
  linear_kernel<32, 32, 8, 32><<<dim3(512, B_), dim3(32, 8), 0, stream>>>(bufB, w1b, b1b, bufA, psum, psq, S1 * KNB);
  stats_kernel<32><<<1, 256, 0, stream>>>(psum, psq, 512, 1.f / (S1 * KNB), mean, rsv);
  norm_relu_kernel<32><<<dim3(2048, B_), 256, 0, stream>>>(bufA, mean, rsv, S1 * KNB * 32);
  linear_kernel<32, 32, 8, 32><<<dim3(512, B_), dim3(32, 8), 0, stream>>>(bufA, w1c, b1c, bufB, psum, psq, S1 * KNB);
  stats_kernel<32><<<1, 256, 0, stream>>>(psum, psq, 512, 1.f / (S1 * KNB), mean, rsv);
  norm_relu_kernel<32><<<dim3(2048, B_), 256, 0, stream>>>(bufB, mean, rsv, S1 * KNB * 32);
  pool1_kernel<<<dim3(512, B_), 256, 0, stream>>>(bufB, f1);

  // ---- stage 2 ----
  fps_kernel<S1, S2, false><<<B_, 512, 0, stream>>>(pc1, out4, pc2, out1);
  knn_kernel<S1, false><<<dim3(S2, B_), 128, 0, stream>>>(pc1, pc2, nidx2, S2);
  gather2_kernel<<<dim3(S2 * KNB / 256, B_), 256, 0, stream>>>(pc1, f1, nidx2, pc2, bufA);
  linear_kernel<35, 64, 4, 32><<<dim3(512, B_), dim3(64, 4), 0, stream>>>(bufA, w2a, b2a, bufB, psum, psq, S2 * KNB);
  stats_kernel<64><<<1, 256, 0, stream>>>(psum, psq, 512, 1.f / (S2 * KNB), mean, rsv);
  norm_relu_kernel<64><<<dim3(2048, B_), 256, 0, stream>>>(bufB, mean, rsv, S2 * KNB * 64);
  linear_kernel<64, 64, 4, 32><<<dim3(512, B_), dim3(64, 4), 0, stream>>>(bufB, w2b, b2b, bufA, psum, psq, S2 * KNB);
  stats_kernel<64><<<1, 256, 0, stream>>>(psum, psq, 512, 1.f / (S2 * KNB), mean, rsv);
  norm_relu_kernel<64><<<dim3(2048, B_), 256, 0, stream>>>(bufA, mean, rsv, S2 * KNB * 64);
  linear_kernel<64, 64, 4, 32><<<dim3(512, B_), dim3(64, 4), 0, stream>>>(bufA, w2c, b2c, bufB, psum, psq, S2 * KNB);
  stats_kernel<64><<<1, 256, 0, stream>>>(psum, psq, 512, 1.f / (S2 * KNB), mean, rsv);
  norm_relu_kernel<64><<<dim3(2048, B_), 256, 0, stream>>>(bufB, mean, rsv, S2 * KNB * 64);
  pool2_kernel<<<dim3(512, B_), 256, 0, stream>>>(bufB, out2);
}

// Round 8
// 7700.723 us; speedup vs baseline: 1.5459x; 1.1054x over previous
//
#include <hip/hip_runtime.h>
#include <hip/hip_bf16.h>
#include <stdint.h>

#define B_  4
#define N0  8192
#define S1  4096
#define S2  2048
#define KNB 32

static constexpr float EPS_IN_ = 1e-5f;

// ---------------- FPS (farthest point sampling) ----------------
// One workgroup per batch (serial argmax chain -> single-CU latency bound).
// Phase A tracks (bv,bi). Wave reduction via DPP (VALU-speed cross-lane, no
// LDS ops): 6-step f32 max (row_shr 1/2/4/8 + row_bcast15/31), readlane 63,
// then i32 min over lanes achieving the max (exact numpy first-argmax
// tie-break). lane0 packs u64 key (bits(val)<<32)|~idx to per-wave parity
// slot; ONE barrier; redundant 8-key u64 max; winner coords via one
// broadcast ds_read_b128 from the float4 LDS table.
// d2 must match numpy exactly: (dx*dx + dy*dy) + dz*dz, all round-nearest,
// NO FMA contraction -> `#pragma clang fp contract(off)` (hipcc default is
// contract=fast-honor-pragmas; __f*_rn alone gets fused!).
template<int N, int NP, bool CHFIRST>
__global__ __launch_bounds__(512)
void fps_kernel(const float* __restrict__ pts,
                float* __restrict__ fidx_out,   // [B,NP] indices as float
                float* __restrict__ newxyz,     // [B,NP,3]
                float* __restrict__ out_t)      // [B,3,NP]
{
  constexpr int NT = 512;
  constexpr int PPT = N / NT;
  const int b = blockIdx.x;
  const int tid = threadIdx.x;
  const int lane = tid & 63;
  const int wid = tid >> 6;

  __shared__ float4 lpk[N];
  __shared__ unsigned long long kq[2][8];
  __shared__ int sidx[NP];

  const float* base = pts + (size_t)b * 3 * N;  // 3N floats/batch in both layouts
  float px[PPT], py[PPT], pz[PPT], dist[PPT];
#pragma unroll
  for (int j = 0; j < PPT; ++j) {
    int p = tid + j * NT;
    float x, y, z;
    if (CHFIRST) { x = base[p];     y = base[N + p];   z = base[2*N + p]; }
    else         { x = base[3*p];   y = base[3*p + 1]; z = base[3*p + 2]; }
    px[j] = x; py[j] = y; pz[j] = z;
    lpk[p] = make_float4(x, y, z, 0.f);
    dist[j] = 1e10f;
  }
  if (tid == 0) sidx[0] = 0;
  __syncthreads();
  float bx = lpk[0].x, by = lpk[0].y, bz = lpk[0].z;

  for (int i = 1; i < NP; ++i) {
    const int par = i & 1;
    // ---- phase A: dist update + (val,idx) argmax (exact numpy arithmetic) ----
    float bv = -1.f; int bi = 0;
#pragma unroll
    for (int j = 0; j < PPT; ++j) {
#pragma clang fp contract(off)
      float dx = px[j] - bx;
      float dy = py[j] - by;
      float dz = pz[j] - bz;
      float d2 = (dx * dx + dy * dy) + dz * dz;   // strict numpy order, no FMA
      float nd = fminf(dist[j], d2);
      dist[j] = nd;
      if (nd > bv) { bv = nd; bi = tid + (j << 9); }   // first-max within thread
    }
    // ---- wave argmax via DPP: f32 max reduce, then i32 min among maxers ----
    // bv >= 0 always (sums of squares; no -0), so identity 0 is safe for max
    // and bit-equality == float equality.
    {
      int x = __float_as_int(bv), t;
      t = __builtin_amdgcn_update_dpp(0, x, 0x111, 0xf, 0xf, false);            // row_shr:1
      x = __float_as_int(fmaxf(__int_as_float(x), __int_as_float(t)));
      t = __builtin_amdgcn_update_dpp(0, x, 0x112, 0xf, 0xf, false);            // row_shr:2
      x = __float_as_int(fmaxf(__int_as_float(x), __int_as_float(t)));
      t = __builtin_amdgcn_update_dpp(0, x, 0x114, 0xf, 0xf, false);            // row_shr:4
      x = __float_as_int(fmaxf(__int_as_float(x), __int_as_float(t)));
      t = __builtin_amdgcn_update_dpp(0, x, 0x118, 0xf, 0xf, false);            // row_shr:8
      x = __float_as_int(fmaxf(__int_as_float(x), __int_as_float(t)));
      t = __builtin_amdgcn_update_dpp(0, x, 0x142, 0xa, 0xf, false);            // row_bcast:15
      x = __float_as_int(fmaxf(__int_as_float(x), __int_as_float(t)));
      t = __builtin_amdgcn_update_dpp(0, x, 0x143, 0xc, 0xf, false);            // row_bcast:31
      x = __float_as_int(fmaxf(__int_as_float(x), __int_as_float(t)));
      const int wmax_bits = __builtin_amdgcn_readlane(x, 63);                   // wave max (uniform)
      int m = (__float_as_int(bv) == wmax_bits) ? bi : 0x7fffffff;
      t = __builtin_amdgcn_update_dpp(0x7fffffff, m, 0x111, 0xf, 0xf, false);
      m = min(m, t);
      t = __builtin_amdgcn_update_dpp(0x7fffffff, m, 0x112, 0xf, 0xf, false);
      m = min(m, t);
      t = __builtin_amdgcn_update_dpp(0x7fffffff, m, 0x114, 0xf, 0xf, false);
      m = min(m, t);
      t = __builtin_amdgcn_update_dpp(0x7fffffff, m, 0x118, 0xf, 0xf, false);
      m = min(m, t);
      t = __builtin_amdgcn_update_dpp(0x7fffffff, m, 0x142, 0xa, 0xf, false);
      m = min(m, t);
      t = __builtin_amdgcn_update_dpp(0x7fffffff, m, 0x143, 0xc, 0xf, false);
      m = min(m, t);
      const int widx = __builtin_amdgcn_readlane(m, 63);                        // min idx among maxers
      if (lane == 0)
        kq[par][wid] = ((unsigned long long)(unsigned)wmax_bits << 32) |
                       (uint32_t)(~(uint32_t)widx);
    }
    __syncthreads();                   // the ONE barrier
    // ---- phase B: redundant 8-key max + broadcast coord read ----
    unsigned long long g = kq[par][0];
#pragma unroll
    for (int w = 1; w < 8; ++w) {
      unsigned long long t2 = kq[par][w];
      g = (t2 > g) ? t2 : g;
    }
    const int wi = (int)(~(uint32_t)g);
    float4 c = lpk[wi];                // one b128 broadcast read
    bx = c.x; by = c.y; bz = c.z;
    if (tid == 0) sidx[i] = wi;
  }
  __syncthreads();
  // outputs: fidx (coalesced), newxyz [B,NP,3], transposed [B,3,NP]
  for (int s = tid; s < NP; s += NT) {
    int id = sidx[s];
    float4 c = lpk[id];
    fidx_out[(size_t)b * NP + s] = (float)id;
    newxyz[((size_t)b * NP + s) * 3 + 0] = c.x;
    newxyz[((size_t)b * NP + s) * 3 + 1] = c.y;
    newxyz[((size_t)b * NP + s) * 3 + 2] = c.z;
    out_t[((size_t)b * 3 + 0) * NP + s] = c.x;
    out_t[((size_t)b * 3 + 1) * NP + s] = c.y;
    out_t[((size_t)b * 3 + 2) * NP + s] = c.z;
  }
}

// ---------------- exact kNN (32 smallest d2, ties by lowest index) ----------------
// One block per query: distances -> LDS float-bit keys, 12-bit-bin histogram
// select, deterministic ordered emit, exact (key,idx) extraction for pivot ties.
template<int N, bool CHFIRST>
__global__ __launch_bounds__(128)
void knn_kernel(const float* __restrict__ pts, const float* __restrict__ query,
                int* __restrict__ nidx, int S)
{
  constexpr int NT = 128;
  constexpr int PPT = N / NT;
  const int q = blockIdx.x, b = blockIdx.y, tid = threadIdx.x;
  __shared__ uint32_t key[N];
  __shared__ uint32_t hist[4096];
  __shared__ uint32_t gsum[NT];
  __shared__ int cnts[NT];
  __shared__ int s_pivot, s_below;
  __shared__ uint32_t wk[2];
  __shared__ int wi[2];

  const float* qp = query + ((size_t)b * S + q) * 3;
  const float qx = qp[0], qy = qp[1], qz = qp[2];
  for (int h = tid; h < 4096; h += NT) hist[h] = 0;
  __syncthreads();
  const float* base = pts + (size_t)b * 3 * N;
  for (int c = 0; c < PPT; ++c) {
    int p = c * NT + tid;
    float x, y, z;
    if (CHFIRST) { x = base[p];     y = base[N + p];   z = base[2*N + p]; }
    else         { x = base[3*p];   y = base[3*p + 1]; z = base[3*p + 2]; }
    float dx = x - qx, dy = y - qy, dz = z - qz;
    float d2 = dx * dx + dy * dy + dz * dz;      // d2 >= 0 -> bits monotone
    uint32_t k = __float_as_uint(d2);
    key[p] = k;
    atomicAdd(&hist[k >> 19], 1u);
  }
  __syncthreads();
  uint32_t ls = 0;
  for (int h = 0; h < 4096 / NT; ++h) ls += hist[tid * (4096 / NT) + h];
  gsum[tid] = ls;
  __syncthreads();
  if (tid == 0) {
    uint32_t cum = 0; int g = 0;
    while (cum + gsum[g] < (uint32_t)KNB) { cum += gsum[g]; ++g; }
    int bin = g * (4096 / NT);
    while (cum + hist[bin] < (uint32_t)KNB) { cum += hist[bin]; ++bin; }
    s_pivot = bin; s_below = (int)cum;
  }
  __syncthreads();
  const uint32_t pivot = (uint32_t)s_pivot;
  const int below = s_below;
  // deterministic ordered emit of all keys strictly below the pivot bin
  int myc = 0;
  for (int c = 0; c < PPT; ++c) {
    int p = c * NT + tid;
    if ((key[p] >> 19) < pivot) ++myc;
  }
  cnts[tid] = myc;
  __syncthreads();
  if (tid == 0) { int run = 0; for (int t = 0; t < NT; ++t) { int v = cnts[t]; cnts[t] = run; run += v; } }
  __syncthreads();
  int* outq = nidx + ((size_t)b * S + q) * KNB;
  int off = cnts[tid];
  for (int c = 0; c < PPT; ++c) {
    int p = c * NT + tid;
    if ((key[p] >> 19) < pivot) outq[off++] = p;
  }
  // remaining picks from the pivot bin: exact (key, idx) min-extraction
  const int r = KNB - below;
  for (int t = 0; t < r; ++t) {
    __syncthreads();
    uint32_t bk = 0xFFFFFFFFu; int bi = N;
    for (int c = 0; c < PPT; ++c) {
      int p = c * NT + tid;
      uint32_t kk = key[p];
      if ((kk & 0x80000000u) == 0 && (kk >> 19) == pivot) {
        if (kk < bk || (kk == bk && p < bi)) { bk = kk; bi = p; }
      }
    }
#pragma unroll
    for (int o = 32; o > 0; o >>= 1) {
      uint32_t ok = __shfl_xor(bk, o);
      int oi = __shfl_xor(bi, o);
      if (ok < bk || (ok == bk && oi < bi)) { bk = ok; bi = oi; }
    }
    if ((tid & 63) == 0) { wk[tid >> 6] = bk; wi[tid >> 6] = bi; }
    __syncthreads();
    if (tid == 0) {
      uint32_t k0 = wk[0]; int i0 = wi[0];
      if (wk[1] < k0 || (wk[1] == k0 && wi[1] < i0)) { k0 = wk[1]; i0 = wi[1]; }
      key[i0] |= 0x80000000u;   // mark taken (bit31 is free: d2 >= 0)
      outq[below + t] = i0;
    }
  }
}

// ---------------- grouping (gather + relative coords) ----------------
__global__ void gather1_kernel(const float* __restrict__ pc, const float* __restrict__ feat,
                               const int* __restrict__ nidx, const float* __restrict__ ctr,
                               __hip_bfloat16* __restrict__ g)   // [B][S1*K][6]
{
  int e = blockIdx.x * 256 + threadIdx.x;
  int b = blockIdx.y;
  if (e >= S1 * KNB) return;
  int s = e >> 5;
  int n = nidx[((size_t)b * S1 + s) * KNB + (e & 31)];
  const float* pb = pc + (size_t)b * 3 * N0;
  const float* fb = feat + (size_t)b * 3 * N0;
  const float* c = ctr + ((size_t)b * S1 + s) * 3;
  __hip_bfloat16* o = g + ((size_t)b * S1 * KNB + e) * 6;
  o[0] = __float2bfloat16(pb[n] - c[0]);
  o[1] = __float2bfloat16(pb[N0 + n] - c[1]);
  o[2] = __float2bfloat16(pb[2 * N0 + n] - c[2]);
  o[3] = __float2bfloat16(fb[n]);
  o[4] = __float2bfloat16(fb[N0 + n]);
  o[5] = __float2bfloat16(fb[2 * N0 + n]);
}

__global__ void gather2_kernel(const float* __restrict__ pc1, const float* __restrict__ f1,
                               const int* __restrict__ nidx, const float* __restrict__ ctr,
                               __hip_bfloat16* __restrict__ g)   // [B][S2*K][35]
{
  int e = blockIdx.x * 256 + threadIdx.x;
  int b = blockIdx.y;
  if (e >= S2 * KNB) return;
  int s = e >> 5;
  int n = nidx[((size_t)b * S2 + s) * KNB + (e & 31)];
  const float* p = pc1 + ((size_t)b * S1 + n) * 3;
  const float* c = ctr + ((size_t)b * S2 + s) * 3;
  const float* f = f1 + ((size_t)b * S1 + n) * 32;
  __hip_bfloat16* o = g + ((size_t)b * S2 * KNB + e) * 35;
  o[0] = __float2bfloat16(p[0] - c[0]);
  o[1] = __float2bfloat16(p[1] - c[1]);
  o[2] = __float2bfloat16(p[2] - c[2]);
#pragma unroll
  for (int ci = 0; ci < 32; ++ci) o[3 + ci] = __float2bfloat16(f[ci]);
}

// ---------------- 1x1-conv linear layer + stats partials ----------------
template<int CIN, int COUT, int TY, int EPT>
__global__ __launch_bounds__(256)
void linear_kernel(const __hip_bfloat16* __restrict__ x, const float* __restrict__ w,
                   const float* __restrict__ bias, __hip_bfloat16* __restrict__ out,
                   float* __restrict__ psum, float* __restrict__ psq, int elems)
{
  const int co = threadIdx.x, ty = threadIdx.y;
  const int blk = blockIdx.x, b = blockIdx.y;
  float wr[CIN];
#pragma unroll
  for (int ci = 0; ci < CIN; ++ci) wr[ci] = w[co * CIN + ci];
  const float bsv = bias[co];
  float ssum = 0.f, ssq = 0.f;
  const int e0 = blk * (TY * EPT) + ty * EPT;
  const __hip_bfloat16* xb = x + (size_t)b * elems * CIN;
  __hip_bfloat16* ob = out + (size_t)b * elems * COUT;
  for (int t = 0; t < EPT; ++t) {
    const int e = e0 + t;
    float acc = bsv;
#pragma unroll
    for (int ci = 0; ci < CIN; ++ci)
      acc += wr[ci] * __bfloat162float(xb[(size_t)e * CIN + ci]);
    ob[(size_t)e * COUT + co] = __float2bfloat16(acc);
    ssum += acc; ssq += acc * acc;
  }
  __shared__ float r1[TY][COUT], r2[TY][COUT];
  r1[ty][co] = ssum; r2[ty][co] = ssq;
  __syncthreads();
  if (ty == 0) {
    float a = 0.f, c = 0.f;
#pragma unroll
    for (int y = 0; y < TY; ++y) { a += r1[y][co]; c += r2[y][co]; }
    psum[((size_t)b * gridDim.x + blk) * COUT + co] = a;
    psq [((size_t)b * gridDim.x + blk) * COUT + co] = c;
  }
}

template<int COUT>
__global__ void stats_kernel(const float* __restrict__ psum, const float* __restrict__ psq,
                             int nblk, float invcnt, float* __restrict__ mean, float* __restrict__ rsv)
{
  int i = threadIdx.x;
  if (i >= B_ * COUT) return;
  int b = i / COUT, co = i % COUT;
  float s = 0.f, qq = 0.f;
  for (int k = 0; k < nblk; ++k) {
    s  += psum[((size_t)b * nblk + k) * COUT + co];
    qq += psq [((size_t)b * nblk + k) * COUT + co];
  }
  float m = s * invcnt;
  float v = qq * invcnt - m * m;
  mean[i] = m;
  rsv[i] = rsqrtf(fmaxf(v, 0.f) + EPS_IN_);
}

template<int COUT>
__global__ __launch_bounds__(256)
void norm_relu_kernel(__hip_bfloat16* __restrict__ buf, const float* __restrict__ mean,
                      const float* __restrict__ rsv, int total)
{
  const int b = blockIdx.y;
  __hip_bfloat16* bb = buf + (size_t)b * total;
  const float* mb = mean + b * COUT;
  const float* rb = rsv + b * COUT;
  for (int p = blockIdx.x * 256 + threadIdx.x; p < total; p += gridDim.x * 256) {
    int co = p & (COUT - 1);
    float v = __bfloat162float(bb[p]);
    v = fmaxf(0.f, (v - mb[co]) * rb[co]);
    bb[p] = __float2bfloat16(v);
  }
}

// ---------------- max-pool over nsample ----------------
__global__ void pool1_kernel(const __hip_bfloat16* __restrict__ buf, float* __restrict__ f1)
{
  int i = blockIdx.x * 256 + threadIdx.x;   // s*32+co
  int b = blockIdx.y;
  if (i >= S1 * 32) return;
  int s = i >> 5, co = i & 31;
  const __hip_bfloat16* bb = buf + ((size_t)b * S1 * KNB + (size_t)s * KNB) * 32 + co;
  float best = -3.4e38f;
  for (int j = 0; j < KNB; ++j) best = fmaxf(best, __bfloat162float(bb[j * 32]));
  f1[((size_t)b * S1 + s) * 32 + co] = best;
}

__global__ void pool2_kernel(const __hip_bfloat16* __restrict__ buf, float* __restrict__ out2)
{
  int i = blockIdx.x * 256 + threadIdx.x;   // s*64+co
  int b = blockIdx.y;
  if (i >= S2 * 64) return;
  int s = i >> 6, co = i & 63;
  const __hip_bfloat16* bb = buf + ((size_t)b * S2 * KNB + (size_t)s * KNB) * 64 + co;
  float best = -3.4e38f;
  for (int j = 0; j < KNB; ++j) best = fmaxf(best, __bfloat162float(bb[j * 64]));
  out2[((size_t)b * 64 + co) * S2 + s] = best;   // [B,64,S2] transposed
}

extern "C" void kernel_launch(void* const* d_in, const int* in_sizes, int n_in,
                              void* d_out, int out_size, void* d_ws, size_t ws_size,
                              hipStream_t stream)
{
  (void)in_sizes; (void)n_in; (void)out_size; (void)ws_size;
  const float* pc   = (const float*)d_in[0];
  const float* feat = (const float*)d_in[1];
  const float* w1a = (const float*)d_in[2];  const float* b1a = (const float*)d_in[3];
  const float* w1b = (const float*)d_in[4];  const float* b1b = (const float*)d_in[5];
  const float* w1c = (const float*)d_in[6];  const float* b1c = (const float*)d_in[7];
  const float* w2a = (const float*)d_in[8];  const float* b2a = (const float*)d_in[9];
  const float* w2b = (const float*)d_in[10]; const float* b2b = (const float*)d_in[11];
  const float* w2c = (const float*)d_in[12]; const float* b2c = (const float*)d_in[13];

  float* out  = (float*)d_out;
  float* out0 = out;                 // pc1^T [4,3,4096]
  float* out1 = out + 49152;         // pc2^T [4,3,2048]
  float* out2 = out + 73728;         // f2^T  [4,64,2048]
  float* out3 = out + 598016;        // idx1  [4,4096] (as float)
  float* out4 = out + 614400;        // idx2  [4,2048] (as float)

  char* wp = (char*)d_ws;
  auto carve = [&](size_t bytes) { char* p = wp; wp += (bytes + 255) & ~(size_t)255; return p; };
  __hip_bfloat16* bufA = (__hip_bfloat16*)carve((size_t)B_ * S1 * KNB * 32 * 2);
  __hip_bfloat16* bufB = (__hip_bfloat16*)carve((size_t)B_ * S1 * KNB * 32 * 2);
  int*   nidx1 = (int*)carve((size_t)B_ * S1 * KNB * 4);
  int*   nidx2 = (int*)carve((size_t)B_ * S2 * KNB * 4);
  float* pc1   = (float*)carve((size_t)B_ * S1 * 3 * 4);
  float* pc2   = (float*)carve((size_t)B_ * S2 * 3 * 4);
  float* f1    = (float*)carve((size_t)B_ * S1 * 32 * 4);
  float* psum  = (float*)carve((size_t)B_ * 512 * 64 * 4);
  float* psq   = (float*)carve((size_t)B_ * 512 * 64 * 4);
  float* mean  = (float*)carve((size_t)B_ * 64 * 4);
  float* rsv   = (float*)carve((size_t)B_ * 64 * 4);

  // ---- stage 1 ----
  fps_kernel<N0, S1, true><<<B_, 512, 0, stream>>>(pc, out3, pc1, out0);
  knn_kernel<N0, true><<<dim3(S1, B_), 128, 0, stream>>>(pc, pc1, nidx1, S1);
  gather1_kernel<<<dim3(S1 * KNB / 256, B_), 256, 0, stream>>>(pc, feat, nidx1, pc1, bufA);
  linear_kernel<6, 32, 8, 32><<<dim3(512, B_), dim3(32, 8), 0, stream>>>(bufA, w1a, b1a, bufB, psum, psq, S1 * KNB);
  stats_kernel<32><<<1, 256, 0, stream>>>(psum, psq, 512, 1.f / (S1 * KNB), mean, rsv);
  norm_relu_kernel<32><<<dim3(2048, B_), 256, 0, stream>>>(bufB, mean, rsv, S1 * KNB * 32);
  linear_kernel<32, 32, 8, 32><<<dim3(512, B_), dim3(32, 8), 0, stream>>>(bufB, w1b, b1b, bufA, psum, psq, S1 * KNB);
  stats_kernel<32><<<1, 256, 0, stream>>>(psum, psq, 512, 1.f / (S1 * KNB), mean, rsv);
  norm_relu_kernel<32><<<dim3(2048, B_), 256, 0, stream>>>(bufA, mean, rsv, S1 * KNB * 32);
  linear_kernel<32, 32, 8, 32><<<dim3(512, B_), dim3(32, 8), 0, stream>>>(bufA, w1c, b1c, bufB, psum, psq, S1 * KNB);
  stats_kernel<32><<<1, 256, 0, stream>>>(psum, psq, 512, 1.f / (S1 * KNB), mean, rsv);
  norm_relu_kernel<32><<<dim3(2048, B_), 256, 0, stream>>>(bufB, mean, rsv, S1 * KNB * 32);
  pool1_kernel<<<dim3(512, B_), 256, 0, stream>>>(bufB, f1);

  // ---- stage 2 ----
  fps_kernel<S1, S2, false><<<B_, 512, 0, stream>>>(pc1, out4, pc2, out1);
  knn_kernel<S1, false><<<dim3(S2, B_), 128, 0, stream>>>(pc1, pc2, nidx2, S2);
  gather2_kernel<<<dim3(S2 * KNB / 256, B_), 256, 0, stream>>>(pc1, f1, nidx2, pc2, bufA);
  linear_kernel<35, 64, 4, 32><<<dim3(512, B_), dim3(64, 4), 0, stream>>>(bufA, w2a, b2a, bufB, psum, psq, S2 * KNB);
  stats_kernel<64><<<1, 256, 0, stream>>>(psum, psq, 512, 1.f / (S2 * KNB), mean, rsv);
  norm_relu_kernel<64><<<dim3(2048, B_), 256, 0, stream>>>(bufB, mean, rsv, S2 * KNB * 64);
  linear_kernel<64, 64, 4, 32><<<dim3(512, B_), dim3(64, 4), 0, stream>>>(bufB, w2b, b2b, bufA, psum, psq, S2 * KNB);
  stats_kernel<64><<<1, 256, 0, stream>>>(psum, psq, 512, 1.f / (S2 * KNB), mean, rsv);
  norm_relu_kernel<64><<<dim3(2048, B_), 256, 0, stream>>>(bufA, mean, rsv, S2 * KNB * 64);
  linear_kernel<64, 64, 4, 32><<<dim3(512, B_), dim3(64, 4), 0, stream>>>(bufA, w2c, b2c, bufB, psum, psq, S2 * KNB);
  stats_kernel<64><<<1, 256, 0, stream>>>(psum, psq, 512, 1.f / (S2 * KNB), mean, rsv);
  norm_relu_kernel<64><<<dim3(2048, B_), 256, 0, stream>>>(bufB, mean, rsv, S2 * KNB * 64);
  pool2_kernel<<<dim3(512, B_), 256, 0, stream>>>(bufB, out2);
}

// Round 9
// 6681.655 us; speedup vs baseline: 1.7817x; 1.1525x over previous
//
#include <hip/hip_runtime.h>
#include <hip/hip_bf16.h>
#include <stdint.h>

#define B_  4
#define N0  8192
#define S1  4096
#define S2  2048
#define KNB 32

static constexpr float EPS_IN_ = 1e-5f;

// ---------------- FPS body (golden index path — unchanged logic from R8) ----------------
// d2 must match numpy exactly: (dx*dx + dy*dy) + dz*dz, all round-nearest,
// NO FMA contraction -> `#pragma clang fp contract(off)`. DPP wave argmax
// (f32 max + i32 min among maxers), u64 key per wave, ONE barrier/iter.
template<int N, int NP, bool CHFIRST>
__device__ __forceinline__ void fps_body(
    const float* __restrict__ base, float* __restrict__ fidx_out,
    float* __restrict__ newxyz, float* __restrict__ out_t,
    float4* __restrict__ lpk, unsigned long long* __restrict__ kq,
    int* __restrict__ sidx)
{
  constexpr int NT = 512;
  constexpr int PPT = N / NT;
  const int tid = threadIdx.x;
  const int lane = tid & 63;
  const int wid = tid >> 6;

  float px[PPT], py[PPT], pz[PPT], dist[PPT];
#pragma unroll
  for (int j = 0; j < PPT; ++j) {
    int p = tid + j * NT;
    float x, y, z;
    if (CHFIRST) { x = base[p];   y = base[N + p];   z = base[2*N + p]; }
    else         { x = base[3*p]; y = base[3*p + 1]; z = base[3*p + 2]; }
    px[j] = x; py[j] = y; pz[j] = z;
    lpk[p] = make_float4(x, y, z, 0.f);
    dist[j] = 1e10f;
  }
  if (tid == 0) sidx[0] = 0;
  __syncthreads();
  float bx = lpk[0].x, by = lpk[0].y, bz = lpk[0].z;

  for (int i = 1; i < NP; ++i) {
    const int par = i & 1;
    float bv = -1.f; int bi = 0;
#pragma unroll
    for (int j = 0; j < PPT; ++j) {
#pragma clang fp contract(off)
      float dx = px[j] - bx;
      float dy = py[j] - by;
      float dz = pz[j] - bz;
      float d2 = (dx * dx + dy * dy) + dz * dz;   // strict numpy order, no FMA
      float nd = fminf(dist[j], d2);
      dist[j] = nd;
      if (nd > bv) { bv = nd; bi = tid + (j << 9); }
    }
    {
      int x = __float_as_int(bv), t;
      t = __builtin_amdgcn_update_dpp(0, x, 0x111, 0xf, 0xf, false);
      x = __float_as_int(fmaxf(__int_as_float(x), __int_as_float(t)));
      t = __builtin_amdgcn_update_dpp(0, x, 0x112, 0xf, 0xf, false);
      x = __float_as_int(fmaxf(__int_as_float(x), __int_as_float(t)));
      t = __builtin_amdgcn_update_dpp(0, x, 0x114, 0xf, 0xf, false);
      x = __float_as_int(fmaxf(__int_as_float(x), __int_as_float(t)));
      t = __builtin_amdgcn_update_dpp(0, x, 0x118, 0xf, 0xf, false);
      x = __float_as_int(fmaxf(__int_as_float(x), __int_as_float(t)));
      t = __builtin_amdgcn_update_dpp(0, x, 0x142, 0xa, 0xf, false);
      x = __float_as_int(fmaxf(__int_as_float(x), __int_as_float(t)));
      t = __builtin_amdgcn_update_dpp(0, x, 0x143, 0xc, 0xf, false);
      x = __float_as_int(fmaxf(__int_as_float(x), __int_as_float(t)));
      const int wmax_bits = __builtin_amdgcn_readlane(x, 63);
      int m = (__float_as_int(bv) == wmax_bits) ? bi : 0x7fffffff;
      t = __builtin_amdgcn_update_dpp(0x7fffffff, m, 0x111, 0xf, 0xf, false);
      m = min(m, t);
      t = __builtin_amdgcn_update_dpp(0x7fffffff, m, 0x112, 0xf, 0xf, false);
      m = min(m, t);
      t = __builtin_amdgcn_update_dpp(0x7fffffff, m, 0x114, 0xf, 0xf, false);
      m = min(m, t);
      t = __builtin_amdgcn_update_dpp(0x7fffffff, m, 0x118, 0xf, 0xf, false);
      m = min(m, t);
      t = __builtin_amdgcn_update_dpp(0x7fffffff, m, 0x142, 0xa, 0xf, false);
      m = min(m, t);
      t = __builtin_amdgcn_update_dpp(0x7fffffff, m, 0x143, 0xc, 0xf, false);
      m = min(m, t);
      const int widx = __builtin_amdgcn_readlane(m, 63);
      if (lane == 0)
        kq[par * 8 + wid] = ((unsigned long long)(unsigned)wmax_bits << 32) |
                            (uint32_t)(~(uint32_t)widx);
    }
    __syncthreads();
    unsigned long long g = kq[par * 8 + 0];
#pragma unroll
    for (int w = 1; w < 8; ++w) {
      unsigned long long t2 = kq[par * 8 + w];
      g = (t2 > g) ? t2 : g;
    }
    const int wi = (int)(~(uint32_t)g);
    float4 c = lpk[wi];
    bx = c.x; by = c.y; bz = c.z;
    if (tid == 0) sidx[i] = wi;
  }
  __syncthreads();
  for (int s = tid; s < NP; s += NT) {
    int id = sidx[s];
    float4 c = lpk[id];
    fidx_out[s] = (float)id;
    newxyz[s * 3 + 0] = c.x;
    newxyz[s * 3 + 1] = c.y;
    newxyz[s * 3 + 2] = c.z;
    out_t[s] = c.x; out_t[NP + s] = c.y; out_t[2 * NP + s] = c.z;
  }
}

template<int N, int NP, bool CHFIRST>
__global__ __launch_bounds__(512)
void fps_kernel(const float* __restrict__ pts, float* __restrict__ fidx_out,
                float* __restrict__ newxyz, float* __restrict__ out_t)
{
  __shared__ float4 lpk[N];
  __shared__ unsigned long long kq[16];
  __shared__ int sidx[NP];
  const int b = blockIdx.x;
  fps_body<N, NP, CHFIRST>(pts + (size_t)b * 3 * N, fidx_out + (size_t)b * NP,
                           newxyz + (size_t)b * NP * 3, out_t + (size_t)b * 3 * NP,
                           lpk, kq, sidx);
}

// ---------------- exact kNN body (NT-generic, parallel scans) ----------------
// Neighbor-SET is exact (32 smallest d2, pivot ties by lowest index); emit
// order is output-invariant (max-pool/IN are order-invariant).
template<int NT, int N, bool CHFIRST>
__device__ __forceinline__ void knn_body(const float* __restrict__ base,
                                         const float* __restrict__ qp,
                                         int* __restrict__ outq, char* __restrict__ sm)
{
  constexpr int PPT = N / NT;
  constexpr int NW = NT / 64;
  constexpr int HB = 4096;
  constexpr int BPT = HB / NT;
  const int tid = threadIdx.x;
  const int lane = tid & 63, wid = tid >> 6;

  uint32_t* key  = (uint32_t*)sm;              // N
  uint32_t* hist = key + N;                    // HB
  uint32_t* wtot = hist + HB;                  // NW
  uint32_t* wk   = wtot + NW;                  // NW
  int*      wi2  = (int*)(wk + NW);            // NW
  int*      sc   = wi2 + NW;                   // 2

  const float qx = qp[0], qy = qp[1], qz = qp[2];
  for (int h = tid; h < HB; h += NT) hist[h] = 0;
  __syncthreads();
  for (int c = 0; c < PPT; ++c) {
    int p = c * NT + tid;
    float x, y, z;
    if (CHFIRST) { x = base[p];   y = base[N + p];   z = base[2*N + p]; }
    else         { x = base[3*p]; y = base[3*p + 1]; z = base[3*p + 2]; }
    float dx = x - qx, dy = y - qy, dz = z - qz;
    float d2 = dx * dx + dy * dy + dz * dz;    // d2 >= 0 -> bits monotone
    uint32_t k = __float_as_uint(d2);
    key[p] = k;
    atomicAdd(&hist[k >> 19], 1u);
  }
  __syncthreads();
  uint32_t ls = 0;
#pragma unroll
  for (int h = 0; h < BPT; ++h) ls += hist[tid * BPT + h];
  // block exclusive scan of ls -> excl
  uint32_t inc = ls;
#pragma unroll
  for (int off = 1; off < 64; off <<= 1) {
    uint32_t t = __shfl_up(inc, (unsigned)off);
    if (lane >= off) inc += t;
  }
  if (lane == 63) wtot[wid] = inc;
  __syncthreads();
  uint32_t woff = 0;
  for (int w = 0; w < wid; ++w) woff += wtot[w];
  uint32_t excl = inc - ls + woff;
  if (excl < (uint32_t)KNB && excl + ls >= (uint32_t)KNB) {   // unique owner
    uint32_t cum = excl; int bin = tid * BPT;
    while (cum + hist[bin] < (uint32_t)KNB) { cum += hist[bin]; ++bin; }
    sc[0] = bin; sc[1] = (int)cum;
  }
  __syncthreads();
  const uint32_t pivot = (uint32_t)sc[0];
  const int below = sc[1];
  // ordered emit of all keys strictly below pivot bin
  int myc = 0;
  for (int c = 0; c < PPT; ++c) {
    int p = c * NT + tid;
    if ((key[p] >> 19) < pivot) ++myc;
  }
  uint32_t inc2 = (uint32_t)myc;
#pragma unroll
  for (int off = 1; off < 64; off <<= 1) {
    uint32_t t = __shfl_up(inc2, (unsigned)off);
    if (lane >= off) inc2 += t;
  }
  if (lane == 63) wtot[wid] = inc2;
  __syncthreads();
  uint32_t woff2 = 0;
  for (int w = 0; w < wid; ++w) woff2 += wtot[w];
  int off2 = (int)(inc2 - (uint32_t)myc + woff2);
  for (int c = 0; c < PPT; ++c) {
    int p = c * NT + tid;
    if ((key[p] >> 19) < pivot) outq[off2++] = p;
  }
  // remaining picks from pivot bin: exact (key, idx) min-extraction
  const int r = KNB - below;
  for (int t = 0; t < r; ++t) {
    __syncthreads();
    uint32_t bk = 0xFFFFFFFFu; int bi = N;
    for (int c = 0; c < PPT; ++c) {
      int p = c * NT + tid;
      uint32_t kk = key[p];
      if ((kk & 0x80000000u) == 0 && (kk >> 19) == pivot) {
        if (kk < bk || (kk == bk && p < bi)) { bk = kk; bi = p; }
      }
    }
#pragma unroll
    for (int o = 32; o > 0; o >>= 1) {
      uint32_t ok = __shfl_xor(bk, o);
      int oi = __shfl_xor(bi, o);
      if (ok < bk || (ok == bk && oi < bi)) { bk = ok; bi = oi; }
    }
    if (lane == 0) { wk[wid] = bk; wi2[wid] = bi; }
    __syncthreads();
    if (tid == 0) {
      uint32_t k0 = wk[0]; int i0 = wi2[0];
      for (int w2 = 1; w2 < NW; ++w2)
        if (wk[w2] < k0 || (wk[w2] == k0 && wi2[w2] < i0)) { k0 = wk[w2]; i0 = wi2[w2]; }
      key[i0] |= 0x80000000u;
      outq[below + t] = i0;
    }
  }
}

// ---------------- fused mid dispatch: fps2 (4 blocks) + knn1 (16384 blocks) ----------------
// Both depend only on pc1/pc (ready). knn1 runs in fps2's ~1.75ms shadow.
__global__ __launch_bounds__(512)
void mid_kernel(const float* __restrict__ pc, const float* __restrict__ pc1,
                float* __restrict__ idx2_out, float* __restrict__ pc2,
                float* __restrict__ out1, int* __restrict__ nidx1)
{
  __shared__ __align__(16) char sm[73856];   // max(fps2 73856, knn1 ~49.3K)
  const int bid = blockIdx.x;
  if (bid < B_) {
    float4* lpk = (float4*)sm;                                    // 65536 B
    unsigned long long* kq = (unsigned long long*)(sm + 65536);   // 128 B
    int* sidx = (int*)(sm + 65536 + 128);                         // 8192 B
    fps_body<S1, S2, false>(pc1 + (size_t)bid * S1 * 3, idx2_out + (size_t)bid * S2,
                            pc2 + (size_t)bid * S2 * 3, out1 + (size_t)bid * 3 * S2,
                            lpk, kq, sidx);
  } else {
    const int idx = bid - B_;
    const int b = idx >> 12;        // S1 = 4096 queries/batch
    const int q = idx & 4095;
    knn_body<512, N0, true>(pc + (size_t)b * 3 * N0,
                            pc1 + ((size_t)b * S1 + q) * 3,
                            nidx1 + ((size_t)b * S1 + q) * KNB, sm);
  }
}

__global__ __launch_bounds__(128)
void knn2_kernel(const float* __restrict__ pc1, const float* __restrict__ pc2,
                 int* __restrict__ nidx2)
{
  __shared__ __align__(16) char sm[33024];
  const int q = blockIdx.x, b = blockIdx.y;
  knn_body<128, S1, false>(pc1 + (size_t)b * S1 * 3, pc2 + ((size_t)b * S2 + q) * 3,
                           nidx2 + ((size_t)b * S2 + q) * KNB, sm);
}

// ---------------- fused gather + linear (layer a) ----------------
__global__ __launch_bounds__(256)
void lin1a_kernel(const float* __restrict__ pc, const float* __restrict__ feat,
                  const int* __restrict__ nidx, const float* __restrict__ ctr,
                  const float* __restrict__ w, const float* __restrict__ bias,
                  __hip_bfloat16* __restrict__ out,
                  float* __restrict__ psum, float* __restrict__ psq)
{
  constexpr int CIN = 6, COUT = 32, TY = 8, EPT = 32, E = TY * EPT;
  __shared__ float xs[E][CIN];
  __shared__ float r1[TY][COUT], r2[TY][COUT];
  const int co = threadIdx.x, ty = threadIdx.y;
  const int tid = ty * COUT + co;
  const int blk = blockIdx.x, b = blockIdx.y;
  {
    int eg = blk * E + tid;
    int s = eg >> 5;
    int n = nidx[((size_t)b * S1 + s) * KNB + (eg & 31)];
    const float* pb = pc + (size_t)b * 3 * N0;
    const float* fb = feat + (size_t)b * 3 * N0;
    const float* c = ctr + ((size_t)b * S1 + s) * 3;
    xs[tid][0] = pb[n] - c[0];
    xs[tid][1] = pb[N0 + n] - c[1];
    xs[tid][2] = pb[2 * N0 + n] - c[2];
    xs[tid][3] = fb[n];
    xs[tid][4] = fb[N0 + n];
    xs[tid][5] = fb[2 * N0 + n];
  }
  __syncthreads();
  float wr[CIN];
#pragma unroll
  for (int ci = 0; ci < CIN; ++ci) wr[ci] = w[co * CIN + ci];
  const float bsv = bias[co];
  float ssum = 0.f, ssq = 0.f;
  __hip_bfloat16* ob = out + ((size_t)b * S1 * KNB + (size_t)blk * E) * COUT;
  for (int t = 0; t < EPT; ++t) {
    int e = ty * EPT + t;
    float acc = bsv;
#pragma unroll
    for (int ci = 0; ci < CIN; ++ci) acc += wr[ci] * xs[e][ci];
    ob[(size_t)e * COUT + co] = __float2bfloat16(acc);
    ssum += acc; ssq += acc * acc;
  }
  r1[ty][co] = ssum; r2[ty][co] = ssq;
  __syncthreads();
  if (ty == 0) {
    float a = 0.f, c = 0.f;
#pragma unroll
    for (int y = 0; y < TY; ++y) { a += r1[y][co]; c += r2[y][co]; }
    psum[((size_t)b * gridDim.x + blk) * COUT + co] = a;
    psq [((size_t)b * gridDim.x + blk) * COUT + co] = c;
  }
}

__global__ __launch_bounds__(256)
void lin2a_kernel(const float* __restrict__ pc1, const float* __restrict__ f1,
                  const int* __restrict__ nidx, const float* __restrict__ ctr,
                  const float* __restrict__ w, const float* __restrict__ bias,
                  __hip_bfloat16* __restrict__ out,
                  float* __restrict__ psum, float* __restrict__ psq)
{
  constexpr int CIN = 35, COUT = 64, TY = 4, EPT = 32, E = TY * EPT, NTHR = 256;
  __shared__ float xs[E][CIN];
  __shared__ float r1[TY][COUT], r2[TY][COUT];
  const int co = threadIdx.x, ty = threadIdx.y;
  const int tid = ty * COUT + co;
  const int blk = blockIdx.x, b = blockIdx.y;
  const int eg0 = blk * E;
  for (int v = tid; v < E * CIN; v += NTHR) {
    int e = v / CIN, ci = v - e * CIN;
    int eg = eg0 + e;
    int s = eg >> 5;
    int n = nidx[((size_t)b * S2 + s) * KNB + (eg & 31)];
    float val;
    if (ci < 3) val = pc1[((size_t)b * S1 + n) * 3 + ci] - ctr[((size_t)b * S2 + s) * 3 + ci];
    else        val = f1[((size_t)b * S1 + n) * 32 + (ci - 3)];
    xs[e][ci] = val;
  }
  __syncthreads();
  float wr[CIN];
#pragma unroll
  for (int ci = 0; ci < CIN; ++ci) wr[ci] = w[co * CIN + ci];
  const float bsv = bias[co];
  float ssum = 0.f, ssq = 0.f;
  __hip_bfloat16* ob = out + ((size_t)b * S2 * KNB + (size_t)eg0) * COUT;
  for (int t = 0; t < EPT; ++t) {
    int e = ty * EPT + t;
    float acc = bsv;
#pragma unroll
    for (int ci = 0; ci < CIN; ++ci) acc += wr[ci] * xs[e][ci];
    ob[(size_t)e * COUT + co] = __float2bfloat16(acc);
    ssum += acc; ssq += acc * acc;
  }
  r1[ty][co] = ssum; r2[ty][co] = ssq;
  __syncthreads();
  if (ty == 0) {
    float a = 0.f, c = 0.f;
#pragma unroll
    for (int y = 0; y < TY; ++y) { a += r1[y][co]; c += r2[y][co]; }
    psum[((size_t)b * gridDim.x + blk) * COUT + co] = a;
    psq [((size_t)b * gridDim.x + blk) * COUT + co] = c;
  }
}

// ---------------- linear with fused input-norm+relu (layers b, c) ----------------
template<int CIN, int COUT, int TY, int EPT>
__global__ __launch_bounds__(COUT * TY)
void linear_norm_kernel(const __hip_bfloat16* __restrict__ x,  // pre-norm activations
                        const float* __restrict__ mean, const float* __restrict__ rsv,
                        const float* __restrict__ w, const float* __restrict__ bias,
                        __hip_bfloat16* __restrict__ out,
                        float* __restrict__ psum, float* __restrict__ psq, int elems)
{
  constexpr int NTHR = COUT * TY;
  constexpr int E = TY * EPT;
  __shared__ float xs[E][CIN];
  __shared__ float sm_[CIN], sr_[CIN];
  __shared__ float r1[TY][COUT], r2[TY][COUT];
  const int co = threadIdx.x, ty = threadIdx.y;
  const int tid = ty * COUT + co;
  const int blk = blockIdx.x, b = blockIdx.y;
  if (tid < CIN) { sm_[tid] = mean[b * CIN + tid]; sr_[tid] = rsv[b * CIN + tid]; }
  const int e0 = blk * E;
  const __hip_bfloat16* xb = x + ((size_t)b * elems + e0) * CIN;
  __syncthreads();
  for (int v = tid; v < E * CIN; v += NTHR) {
    int e = v / CIN, ci = v - (v / CIN) * CIN;
    float val = __bfloat162float(xb[v]);
    xs[e][ci] = fmaxf(0.f, (val - sm_[ci]) * sr_[ci]);
  }
  __syncthreads();
  float wr[CIN];
#pragma unroll
  for (int ci = 0; ci < CIN; ++ci) wr[ci] = w[co * CIN + ci];
  const float bsv = bias[co];
  float ssum = 0.f, ssq = 0.f;
  __hip_bfloat16* ob = out + ((size_t)b * elems + e0) * COUT;
  for (int t = 0; t < EPT; ++t) {
    int e = ty * EPT + t;
    float acc = bsv;
#pragma unroll
    for (int ci = 0; ci < CIN; ++ci) acc += wr[ci] * xs[e][ci];
    ob[(size_t)e * COUT + co] = __float2bfloat16(acc);
    ssum += acc; ssq += acc * acc;
  }
  r1[ty][co] = ssum; r2[ty][co] = ssq;
  __syncthreads();
  if (ty == 0) {
    float a = 0.f, c = 0.f;
#pragma unroll
    for (int y = 0; y < TY; ++y) { a += r1[y][co]; c += r2[y][co]; }
    psum[((size_t)b * gridDim.x + blk) * COUT + co] = a;
    psq [((size_t)b * gridDim.x + blk) * COUT + co] = c;
  }
}

template<int COUT>
__global__ void stats_kernel(const float* __restrict__ psum, const float* __restrict__ psq,
                             int nblk, float invcnt, float* __restrict__ mean,
                             float* __restrict__ rsv)
{
  int i = threadIdx.x;
  if (i >= B_ * COUT) return;
  int b = i / COUT, co = i % COUT;
  float s = 0.f, qq = 0.f;
  for (int k = 0; k < nblk; ++k) {
    s  += psum[((size_t)b * nblk + k) * COUT + co];
    qq += psq [((size_t)b * nblk + k) * COUT + co];
  }
  float m = s * invcnt;
  float v = qq * invcnt - m * m;
  mean[i] = m;
  rsv[i] = rsqrtf(fmaxf(v, 0.f) + EPS_IN_);
}

// ---------------- max-pool with fused final norm+relu ----------------
// relu((max-m)*r) == max then norm since rsv>0 makes the transform monotone.
__global__ void pool1_kernel(const __hip_bfloat16* __restrict__ buf,
                             const float* __restrict__ mean, const float* __restrict__ rsv,
                             float* __restrict__ f1)
{
  int i = blockIdx.x * 256 + threadIdx.x;
  int b = blockIdx.y;
  if (i >= S1 * 32) return;
  int s = i >> 5, co = i & 31;
  const __hip_bfloat16* bb = buf + ((size_t)b * S1 * KNB + (size_t)s * KNB) * 32 + co;
  float best = -3.4e38f;
  for (int j = 0; j < KNB; ++j) best = fmaxf(best, __bfloat162float(bb[j * 32]));
  best = fmaxf(0.f, (best - mean[b * 32 + co]) * rsv[b * 32 + co]);
  f1[((size_t)b * S1 + s) * 32 + co] = best;
}

__global__ void pool2_kernel(const __hip_bfloat16* __restrict__ buf,
                             const float* __restrict__ mean, const float* __restrict__ rsv,
                             float* __restrict__ out2)
{
  int i = blockIdx.x * 256 + threadIdx.x;
  int b = blockIdx.y;
  if (i >= S2 * 64) return;
  int s = i >> 6, co = i & 63;
  const __hip_bfloat16* bb = buf + ((size_t)b * S2 * KNB + (size_t)s * KNB) * 64 + co;
  float best = -3.4e38f;
  for (int j = 0; j < KNB; ++j) best = fmaxf(best, __bfloat162float(bb[j * 64]));
  best = fmaxf(0.f, (best - mean[b * 64 + co]) * rsv[b * 64 + co]);
  out2[((size_t)b * 64 + co) * S2 + s] = best;   // [B,64,S2] transposed
}

extern "C" void kernel_launch(void* const* d_in, const int* in_sizes, int n_in,
                              void* d_out, int out_size, void* d_ws, size_t ws_size,
                              hipStream_t stream)
{
  (void)in_sizes; (void)n_in; (void)out_size; (void)ws_size;
  const float* pc   = (const float*)d_in[0];
  const float* feat = (const float*)d_in[1];
  const float* w1a = (const float*)d_in[2];  const float* b1a = (const float*)d_in[3];
  const float* w1b = (const float*)d_in[4];  const float* b1b = (const float*)d_in[5];
  const float* w1c = (const float*)d_in[6];  const float* b1c = (const float*)d_in[7];
  const float* w2a = (const float*)d_in[8];  const float* b2a = (const float*)d_in[9];
  const float* w2b = (const float*)d_in[10]; const float* b2b = (const float*)d_in[11];
  const float* w2c = (const float*)d_in[12]; const float* b2c = (const float*)d_in[13];

  float* out  = (float*)d_out;
  float* out0 = out;                 // pc1^T [4,3,4096]
  float* out1 = out + 49152;         // pc2^T [4,3,2048]
  float* out2 = out + 73728;         // f2^T  [4,64,2048]
  float* out3 = out + 598016;        // idx1  [4,4096] (as float)
  float* out4 = out + 614400;        // idx2  [4,2048] (as float)

  char* wp = (char*)d_ws;
  auto carve = [&](size_t bytes) { char* p = wp; wp += (bytes + 255) & ~(size_t)255; return p; };
  __hip_bfloat16* bufA = (__hip_bfloat16*)carve((size_t)B_ * S1 * KNB * 32 * 2);
  __hip_bfloat16* bufB = (__hip_bfloat16*)carve((size_t)B_ * S1 * KNB * 32 * 2);
  int*   nidx1 = (int*)carve((size_t)B_ * S1 * KNB * 4);
  int*   nidx2 = (int*)carve((size_t)B_ * S2 * KNB * 4);
  float* pc1   = (float*)carve((size_t)B_ * S1 * 3 * 4);
  float* pc2   = (float*)carve((size_t)B_ * S2 * 3 * 4);
  float* f1    = (float*)carve((size_t)B_ * S1 * 32 * 4);
  float* psum  = (float*)carve((size_t)B_ * 512 * 64 * 4);
  float* psq   = (float*)carve((size_t)B_ * 512 * 64 * 4);
  float* mean  = (float*)carve((size_t)B_ * 64 * 4);
  float* rsv   = (float*)carve((size_t)B_ * 64 * 4);

  // ---- stage 1 ----
  fps_kernel<N0, S1, true><<<B_, 512, 0, stream>>>(pc, out3, pc1, out0);
  mid_kernel<<<B_ + S1 * B_, 512, 0, stream>>>(pc, pc1, out4, pc2, out1, nidx1);
  lin1a_kernel<<<dim3(512, B_), dim3(32, 8), 0, stream>>>(pc, feat, nidx1, pc1, w1a, b1a, bufA, psum, psq);
  stats_kernel<32><<<1, 256, 0, stream>>>(psum, psq, 512, 1.f / (S1 * KNB), mean, rsv);
  linear_norm_kernel<32, 32, 8, 32><<<dim3(512, B_), dim3(32, 8), 0, stream>>>(bufA, mean, rsv, w1b, b1b, bufB, psum, psq, S1 * KNB);
  stats_kernel<32><<<1, 256, 0, stream>>>(psum, psq, 512, 1.f / (S1 * KNB), mean, rsv);
  linear_norm_kernel<32, 32, 8, 32><<<dim3(512, B_), dim3(32, 8), 0, stream>>>(bufB, mean, rsv, w1c, b1c, bufA, psum, psq, S1 * KNB);
  stats_kernel<32><<<1, 256, 0, stream>>>(psum, psq, 512, 1.f / (S1 * KNB), mean, rsv);
  pool1_kernel<<<dim3(512, B_), 256, 0, stream>>>(bufA, mean, rsv, f1);

  // ---- stage 2 ----
  knn2_kernel<<<dim3(S2, B_), 128, 0, stream>>>(pc1, pc2, nidx2);
  lin2a_kernel<<<dim3(512, B_), dim3(64, 4), 0, stream>>>(pc1, f1, nidx2, pc2, w2a, b2a, bufB, psum, psq);
  stats_kernel<64><<<1, 256, 0, stream>>>(psum, psq, 512, 1.f / (S2 * KNB), mean, rsv);
  linear_norm_kernel<64, 64, 4, 32><<<dim3(512, B_), dim3(64, 4), 0, stream>>>(bufB, mean, rsv, w2b, b2b, bufA, psum, psq, S2 * KNB);
  stats_kernel<64><<<1, 256, 0, stream>>>(psum, psq, 512, 1.f / (S2 * KNB), mean, rsv);
  linear_norm_kernel<64, 64, 4, 32><<<dim3(512, B_), dim3(64, 4), 0, stream>>>(bufA, mean, rsv, w2c, b2c, bufB, psum, psq, S2 * KNB);
  stats_kernel<64><<<1, 256, 0, stream>>>(psum, psq, 512, 1.f / (S2 * KNB), mean, rsv);
  pool2_kernel<<<dim3(512, B_), 256, 0, stream>>>(bufB, mean, rsv, out2);
}